// Round 1
// baseline (4075.235 us; speedup 1.0000x reference)
//
#include <hip/hip_runtime.h>
#include <math.h>

// ---------------------------------------------------------------------------
// GMVAE fused pipeline, fp32 correctness-first baseline.
// B=16 S=256 D=512 H_heads=4 dh=128 L=64 K=20 MC=10 EM_ITERS=5
// ---------------------------------------------------------------------------

#define BATCH 16
#define SEQ 256
#define DIM 512
#define NH 4
#define DH 128
#define LD 64      // latent dim L
#define KC 20      // clusters
#define MC 10
#define NPTS 2560  // S*MC per batch
#define BS_TOT 4096  // B*S
#define NROWS 40960  // B*S*MC
#define LOG_NORM (-0.9189385332046727f)

__device__ inline float warpReduceSum(float v) {
    for (int o = 32; o > 0; o >>= 1) v += __shfl_down(v, o);
    return v;
}
__device__ inline float warpReduceMax(float v) {
    for (int o = 32; o > 0; o >>= 1) v = fmaxf(v, __shfl_down(v, o));
    return v;
}

// ---------------------------------------------------------------------------
// Generic batched tiled GEMM: C = f(alpha * A@B(^T) [+bias] [relu]) [+R] ;
// optional fused squared-diff loss vs Href (decoder last layer).
// Tiles: 128x128, BK=16, 256 threads, 8x8 per-thread microtile.
// All M,N assumed multiples of 128; K multiple of 16 (true for every call).
// ---------------------------------------------------------------------------
template<bool TRANS_B, bool HAS_BIAS, bool RELU, bool RESID, bool SQLOSS>
__global__ __launch_bounds__(256)
void gemm_k(const float* __restrict__ A, const float* __restrict__ Bm,
            float* __restrict__ C,
            const float* __restrict__ bias,
            const float* __restrict__ R,
            const float* __restrict__ Href,
            float* __restrict__ lossAcc,
            int K, int lda, int ldb, int ldc,
            float alpha, int nh,
            long aSB, long aSH, long bSB, long bSH,
            long cSB, long cSH, long rSB, long rSH,
            int mOffset)
{
    __shared__ float As[16][132];   // k-major (transposed) A tile
    __shared__ float Bs[16][132];   // k-major B tile
    __shared__ float redS[4];

    const int t = threadIdx.x;
    const int bz = blockIdx.z;
    const int bb = bz / nh, hh = bz % nh;
    A += bb * aSB + hh * aSH;
    Bm += bb * bSB + hh * bSH;
    C += bb * cSB + hh * cSH;
    if (RESID) R += bb * rSB + hh * rSH;

    const int m0g = blockIdx.y * 128;
    const int n0g = blockIdx.x * 128;
    const int tx = t & 15, ty = t >> 4;

    float acc[8][8];
#pragma unroll
    for (int i = 0; i < 8; i++)
#pragma unroll
        for (int j = 0; j < 8; j++) acc[i][j] = 0.f;

    const int nkt = K >> 4;
    for (int kt = 0; kt < nkt; ++kt) {
        // stage A (transpose 128x16 -> As[k][m])
#pragma unroll
        for (int p = 0; p < 2; p++) {
            int fidx = t + p * 256;
            int row = fidx >> 2, c4 = fidx & 3;
            const float4 av = *(const float4*)&A[(long)(m0g + row) * lda + kt * 16 + c4 * 4];
            As[c4 * 4 + 0][row] = av.x;
            As[c4 * 4 + 1][row] = av.y;
            As[c4 * 4 + 2][row] = av.z;
            As[c4 * 4 + 3][row] = av.w;
        }
        if (!TRANS_B) {
#pragma unroll
            for (int p = 0; p < 2; p++) {
                int fidx = t + p * 256;
                int kk = fidx >> 5, c4 = fidx & 31;
                const float4 bv = *(const float4*)&Bm[(long)(kt * 16 + kk) * ldb + n0g + c4 * 4];
                *(float4*)&Bs[kk][c4 * 4] = bv;
            }
        } else {
#pragma unroll
            for (int p = 0; p < 2; p++) {
                int fidx = t + p * 256;
                int row = fidx >> 2, c4 = fidx & 3;  // row = n
                const float4 bv = *(const float4*)&Bm[(long)(n0g + row) * ldb + kt * 16 + c4 * 4];
                Bs[c4 * 4 + 0][row] = bv.x;
                Bs[c4 * 4 + 1][row] = bv.y;
                Bs[c4 * 4 + 2][row] = bv.z;
                Bs[c4 * 4 + 3][row] = bv.w;
            }
        }
        __syncthreads();
#pragma unroll
        for (int k = 0; k < 16; k++) {
            float a[8], b[8];
            *(float4*)&a[0] = *(const float4*)&As[k][ty * 8];
            *(float4*)&a[4] = *(const float4*)&As[k][ty * 8 + 4];
            *(float4*)&b[0] = *(const float4*)&Bs[k][tx * 8];
            *(float4*)&b[4] = *(const float4*)&Bs[k][tx * 8 + 4];
#pragma unroll
            for (int i = 0; i < 8; i++)
#pragma unroll
                for (int j = 0; j < 8; j++)
                    acc[i][j] = fmaf(a[i], b[j], acc[i][j]);
        }
        __syncthreads();
    }

    float lsum = 0.f;
#pragma unroll
    for (int i = 0; i < 8; i++) {
        const int mg = m0g + ty * 8 + i;
        float v[8];
#pragma unroll
        for (int j = 0; j < 8; j++) {
            const int ng = n0g + tx * 8 + j;
            float x = alpha * acc[i][j];
            if (HAS_BIAS) x += bias[ng];
            if (RELU) x = fmaxf(x, 0.f);
            if (RESID) x += R[(long)mg * ldc + ng];
            if (SQLOSS) {
                const float d = x - Href[(long)((mOffset + mg) / MC) * DIM + ng];
                lsum = fmaf(d, d, lsum);
            }
            v[j] = x;
        }
        if (!SQLOSS) {
            *(float4*)&C[(long)mg * ldc + n0g + tx * 8] = *(float4*)&v[0];
            *(float4*)&C[(long)mg * ldc + n0g + tx * 8 + 4] = *(float4*)&v[4];
        }
    }
    if (SQLOSS) {
        lsum = warpReduceSum(lsum);
        if ((t & 63) == 0) redS[t >> 6] = lsum;
        __syncthreads();
        if (t == 0) atomicAdd(lossAcc, redS[0] + redS[1] + redS[2] + redS[3]);
    }
}

// ---------------------------------------------------------------------------
// Row softmax over the 16384x256 score matrix. One wave per row.
// ---------------------------------------------------------------------------
__global__ __launch_bounds__(256)
void softmax_rows(float* __restrict__ S)
{
    const long row = (long)blockIdx.x * 4 + (threadIdx.x >> 6);
    const int lane = threadIdx.x & 63;
    float4 v = *(float4*)&S[row * 256 + lane * 4];
    float mx = fmaxf(fmaxf(v.x, v.y), fmaxf(v.z, v.w));
    mx = warpReduceMax(mx);
    mx = __shfl(mx, 0);
    v.x = expf(v.x - mx); v.y = expf(v.y - mx);
    v.z = expf(v.z - mx); v.w = expf(v.w - mx);
    float s = v.x + v.y + v.z + v.w;
    s = warpReduceSum(s);
    s = __shfl(s, 0);
    const float inv = 1.f / s;
    v.x *= inv; v.y *= inv; v.z *= inv; v.w *= inv;
    *(float4*)&S[row * 256 + lane * 4] = v;
}

// ---------------------------------------------------------------------------
// z = mean + eps * exp(0.5*logvar); stats = [mean | logvar] per (b,s).
// Operates on float4 granularity over the 2.62M-element z tensor.
// ---------------------------------------------------------------------------
__global__ __launch_bounds__(256)
void zgen(const float* __restrict__ stats, const float* __restrict__ eps,
          float* __restrict__ z)
{
    const int idx = blockIdx.x * 256 + threadIdx.x;  // float4 index
    const int bs = idx / 160;                        // 640 floats per (b,s)
    const int r = idx % 160;
    const int l4 = r % 16;
    const float4 e = ((const float4*)eps)[idx];
    const float4 mn = ((const float4*)stats)[bs * 32 + l4];
    const float4 lv = ((const float4*)stats)[bs * 32 + 16 + l4];
    float4 zz;
    zz.x = fmaf(e.x, expf(0.5f * lv.x), mn.x);
    zz.y = fmaf(e.y, expf(0.5f * lv.y), mn.y);
    zz.z = fmaf(e.z, expf(0.5f * lv.z), mn.z);
    zz.w = fmaf(e.w, expf(0.5f * lv.w), mn.w);
    ((float4*)z)[idx] = zz;
}

// ---------------------------------------------------------------------------
// EM init: gather mu from z at init_idx, logPi = -log(K), zero accumulators.
// grid = 16 blocks (per batch), 256 threads.
// ---------------------------------------------------------------------------
__global__ void em_init(const float* __restrict__ z, const int* __restrict__ init_idx,
                        float* __restrict__ mu, float* __restrict__ logPi,
                        float* __restrict__ musum, float* __restrict__ NkG)
{
    const int b = blockIdx.x, t = threadIdx.x;
    for (int i = t; i < KC * LD; i += 256) {
        const int k = i >> 6, l = i & 63;
        const int idx = init_idx[b * KC + k];
        mu[b * KC * LD + i] = z[((long)b * NPTS + idx) * LD + l];
        musum[b * KC * LD + i] = 0.f;
    }
    if (t < KC) {
        logPi[b * KC + t] = -logf((float)KC);
        NkG[b * KC + t] = 0.f;
    }
}

// ---------------------------------------------------------------------------
// One EM E+accumulate step. grid (10 tiles, 16 batches) x 256 threads.
// Each thread owns one point: 20 dots vs mu (LDS), softmax -> postS;
// then a block mini-GEMM accumulates musum (global atomics, 5 outputs/thread)
// and per-wave reductions accumulate Nk.
// ---------------------------------------------------------------------------
__global__ __launch_bounds__(256)
void em_step(const float* __restrict__ z, const float* __restrict__ mu,
             const float* __restrict__ logPi,
             float* __restrict__ musum, float* __restrict__ NkG)
{
    __shared__ float muS[KC][65];
    __shared__ float m2lp[KC];
    __shared__ float postS[KC][256];
    __shared__ float NkS[KC];

    const int tile = blockIdx.x, b = blockIdx.y, t = threadIdx.x;

    for (int i = t; i < KC * LD; i += 256) muS[i >> 6][i & 63] = mu[b * KC * LD + i];
    __syncthreads();
    if (t < KC) {
        float s = 0.f;
        for (int l = 0; l < LD; l++) { const float m = muS[t][l]; s = fmaf(m, m, s); }
        m2lp[t] = -0.5f * s + logPi[b * KC + t];
    }
    __syncthreads();

    // phase 1: posteriors (the -0.5*x2 term is constant in k -> cancels in softmax)
    const long n = (long)tile * 256 + t;
    const float* zr = &z[((long)b * NPTS + n) * LD];
    float acc[KC];
#pragma unroll
    for (int k = 0; k < KC; k++) acc[k] = 0.f;
#pragma unroll
    for (int l4 = 0; l4 < 16; l4++) {
        const float4 zv = ((const float4*)zr)[l4];
#pragma unroll
        for (int k = 0; k < KC; k++) {
            acc[k] = fmaf(zv.x, muS[k][l4 * 4 + 0], acc[k]);
            acc[k] = fmaf(zv.y, muS[k][l4 * 4 + 1], acc[k]);
            acc[k] = fmaf(zv.z, muS[k][l4 * 4 + 2], acc[k]);
            acc[k] = fmaf(zv.w, muS[k][l4 * 4 + 3], acc[k]);
        }
    }
    float mx = -1e30f;
    float llv[KC];
#pragma unroll
    for (int k = 0; k < KC; k++) { llv[k] = acc[k] + m2lp[k]; mx = fmaxf(mx, llv[k]); }
    float s = 0.f;
#pragma unroll
    for (int k = 0; k < KC; k++) { llv[k] = expf(llv[k] - mx); s += llv[k]; }
    const float inv = 1.f / s;
#pragma unroll
    for (int k = 0; k < KC; k++) postS[k][t] = llv[k] * inv;
    __syncthreads();

    // Nk: 5 clusters per wave
    const int lane = t & 63, w = t >> 6;
#pragma unroll
    for (int kk = 0; kk < 5; kk++) {
        const int k = w * 5 + kk;
        float p = postS[k][lane] + postS[k][lane + 64] + postS[k][lane + 128] + postS[k][lane + 192];
        p = warpReduceSum(p);
        if (lane == 0) NkS[k] = p;
    }
    __syncthreads();

    // phase 2: musum[k][l] += sum_n post[k][n]*z[n][l]; 5 (k,l) outputs/thread
    const float* zb = &z[((long)b * NPTS + (long)tile * 256) * LD];
#pragma unroll
    for (int j = 0; j < 5; j++) {
        const int o = t + j * 256;
        const int k = o >> 6, l = o & 63;
        float sacc = 0.f;
        for (int n2 = 0; n2 < 256; n2++)
            sacc = fmaf(postS[k][n2], zb[n2 * LD + l], sacc);
        atomicAdd(&musum[b * KC * LD + o], sacc);
    }
    if (t < KC) atomicAdd(&NkG[b * KC + t], NkS[t]);
}

// ---------------------------------------------------------------------------
// EM M-step finalize: pi/logPi and mu from accumulators; re-zero accumulators.
// grid = 16 blocks x 64 threads.
// ---------------------------------------------------------------------------
__global__ void em_update(float* __restrict__ mu, float* __restrict__ logPi,
                          float* __restrict__ musum, float* __restrict__ NkG)
{
    __shared__ float Nk[KC];
    const int b = blockIdx.x, t = threadIdx.x;
    if (t < KC) Nk[t] = NkG[b * KC + t];
    __syncthreads();
    float s = 0.f;
    for (int k = 0; k < KC; k++) s += Nk[k];
    if (t < KC) logPi[b * KC + t] = logf(Nk[t] / s);
    for (int i = t; i < KC * LD; i += 64) {
        const int k = i >> 6;
        mu[b * KC * LD + i] = musum[b * KC * LD + i] / Nk[k];
        musum[b * KC * LD + i] = 0.f;
    }
    __syncthreads();
    if (t < KC) NkG[b * KC + t] = 0.f;
}

// ---------------------------------------------------------------------------
// KL: per point log_qz - log_pz, block-reduced, atomically accumulated.
// log_qz = -0.5*(sum logvar + sum eps^2) + L*LOG_NORM  (since z-mean = eps*std)
// log_pz = logsumexp_k(-0.5*x2 + z.mu_k - 0.5*m2_k + logpi_k) + L*LOG_NORM
// ---------------------------------------------------------------------------
__global__ __launch_bounds__(256)
void kl_kernel(const float* __restrict__ z, const float* __restrict__ stats,
               const float* __restrict__ eps,
               const float* __restrict__ mu, const float* __restrict__ logPi,
               float* __restrict__ klAcc)
{
    __shared__ float muS[KC][65];
    __shared__ float m2lp[KC];
    __shared__ float redS[4];

    const int tile = blockIdx.x, b = blockIdx.y, t = threadIdx.x;

    for (int i = t; i < KC * LD; i += 256) muS[i >> 6][i & 63] = mu[b * KC * LD + i];
    __syncthreads();
    if (t < KC) {
        float s = 0.f;
        for (int l = 0; l < LD; l++) { const float m = muS[t][l]; s = fmaf(m, m, s); }
        m2lp[t] = -0.5f * s + logPi[b * KC + t];
    }
    __syncthreads();

    const int n = tile * 256 + t;
    const int sidx = n / MC, m = n % MC;
    const long bs = (long)b * SEQ + sidx;
    const float* zr = &z[((long)b * NPTS + n) * LD];

    float acc[KC];
#pragma unroll
    for (int k = 0; k < KC; k++) acc[k] = 0.f;
    float x2 = 0.f;
#pragma unroll
    for (int l4 = 0; l4 < 16; l4++) {
        const float4 zv = ((const float4*)zr)[l4];
        x2 = fmaf(zv.x, zv.x, fmaf(zv.y, zv.y, fmaf(zv.z, zv.z, fmaf(zv.w, zv.w, x2))));
#pragma unroll
        for (int k = 0; k < KC; k++) {
            acc[k] = fmaf(zv.x, muS[k][l4 * 4 + 0], acc[k]);
            acc[k] = fmaf(zv.y, muS[k][l4 * 4 + 1], acc[k]);
            acc[k] = fmaf(zv.z, muS[k][l4 * 4 + 2], acc[k]);
            acc[k] = fmaf(zv.w, muS[k][l4 * 4 + 3], acc[k]);
        }
    }
    float mx = -1e30f;
    float llv[KC];
#pragma unroll
    for (int k = 0; k < KC; k++) { llv[k] = acc[k] + m2lp[k]; mx = fmaxf(mx, llv[k]); }
    float s = 0.f;
#pragma unroll
    for (int k = 0; k < KC; k++) s += expf(llv[k] - mx);
    const float log_pz = -0.5f * x2 + mx + logf(s) + LD * LOG_NORM;

    const float* lvr = &stats[bs * 128 + 64];
    const float* er = &eps[(bs * MC + m) * LD];
    float slv = 0.f, se2 = 0.f;
#pragma unroll
    for (int l4 = 0; l4 < 16; l4++) {
        const float4 lv = ((const float4*)lvr)[l4];
        slv += lv.x + lv.y + lv.z + lv.w;
        const float4 e = ((const float4*)er)[l4];
        se2 = fmaf(e.x, e.x, fmaf(e.y, e.y, fmaf(e.z, e.z, fmaf(e.w, e.w, se2))));
    }
    const float log_qz = -0.5f * (slv + se2) + LD * LOG_NORM;

    float v = log_qz - log_pz;
    v = warpReduceSum(v);
    if ((t & 63) == 0) redS[t >> 6] = v;
    __syncthreads();
    if (t == 0) atomicAdd(klAcc, redS[0] + redS[1] + redS[2] + redS[3]);
}

__global__ void finalize(const float* __restrict__ scal, float* __restrict__ out)
{
    if (threadIdx.x == 0) {
        out[0] = scal[0] * (1.f / (float)NROWS);
        out[1] = scal[1] * (1.f / (float)NROWS);
    }
}

// ---------------------------------------------------------------------------
extern "C" void kernel_launch(void* const* d_in, const int* in_sizes, int n_in,
                              void* d_out, int out_size, void* d_ws, size_t ws_size,
                              hipStream_t stream)
{
    const float* H   = (const float*)d_in[0];
    const float* eps = (const float*)d_in[1];
    const float* wq  = (const float*)d_in[2];
    const float* bq  = (const float*)d_in[3];
    const float* wk  = (const float*)d_in[4];
    const float* bk  = (const float*)d_in[5];
    const float* wv  = (const float*)d_in[6];
    const float* bv  = (const float*)d_in[7];
    const float* wo  = (const float*)d_in[8];
    const float* bo  = (const float*)d_in[9];
    const float* wz  = (const float*)d_in[10];
    const float* bz  = (const float*)d_in[11];
    const float* w1  = (const float*)d_in[12];
    const float* b1  = (const float*)d_in[13];
    const float* w2  = (const float*)d_in[14];
    const float* b2  = (const float*)d_in[15];
    const float* w3  = (const float*)d_in[16];
    const float* b3  = (const float*)d_in[17];
    const int* init_idx = (const int*)d_in[18];
    float* out = (float*)d_out;
    float* wsf = (float*)d_ws;

    // ws layout (float offsets); total ~20.0M floats = 80 MB
    const long o_scal  = 0;                       // [0]=rec_sum [1]=kl_sum
    const long o_NkG   = 1024;                    // 320
    const long o_musum = 2048;                    // 20480
    const long o_logpi = 23552;                   // 320
    const long o_mu    = 24576;                   // 20480
    const long o_q     = 45056;                   // 2097152 each
    const long o_k     = o_q  + 2097152;
    const long o_v     = o_k  + 2097152;
    const long o_o     = o_v  + 2097152;
    const long o_hA    = o_o  + 2097152;
    const long o_hB    = o_hA + 2097152;
    const long o_sc    = o_hB + 2097152;          // scores 4194304
    const long o_stats = o_sc + 4194304;          // 524288
    const long o_z     = o_stats + 524288;        // 2621440
    // decoder activations overlay the dead q/k/v/o region (4096-row chunks)
    const long o_d1 = o_q;                        // 4194304 (q+k region)
    const long o_d2 = o_v;                        // 4194304 (v+o region)

    float* qb = wsf + o_q;  float* kb = wsf + o_k;  float* vb = wsf + o_v;
    float* ob = wsf + o_o;  float* hA = wsf + o_hA; float* hB = wsf + o_hB;
    float* sc = wsf + o_sc; float* st = wsf + o_stats; float* zb = wsf + o_z;
    float* d1 = wsf + o_d1; float* d2 = wsf + o_d2;
    float* scal = wsf + o_scal;

    hipMemsetAsync(scal, 0, 64, stream);  // rec/kl accumulators

    const dim3 blk(256);
    const long SD = (long)SEQ * DIM;  // 131072
    const float inv_sqrt_d = 0.044194173824159216f;  // 1/sqrt(512)

    // ---- 2x MAB ----
    const float* hin = H;
    float* houts[2] = { hA, hB };
    for (int i = 0; i < 2; i++) {
        const long woff = (long)i * DIM * DIM, boff = (long)i * DIM;
        // q,k,v projections
        gemm_k<false, true, false, false, false><<<dim3(4, 32, 1), blk, 0, stream>>>(
            hin, wq + woff, qb, bq + boff, nullptr, nullptr, nullptr,
            512, 512, 512, 512, 1.f, 1, 0, 0, 0, 0, 0, 0, 0, 0, 0);
        gemm_k<false, true, false, false, false><<<dim3(4, 32, 1), blk, 0, stream>>>(
            hin, wk + woff, kb, bk + boff, nullptr, nullptr, nullptr,
            512, 512, 512, 512, 1.f, 1, 0, 0, 0, 0, 0, 0, 0, 0, 0);
        gemm_k<false, true, false, false, false><<<dim3(4, 32, 1), blk, 0, stream>>>(
            hin, wv + woff, vb, bv + boff, nullptr, nullptr, nullptr,
            512, 512, 512, 512, 1.f, 1, 0, 0, 0, 0, 0, 0, 0, 0, 0);
        // scores = q @ k^T / sqrt(D), per (b,h)
        gemm_k<true, false, false, false, false><<<dim3(2, 2, 64), blk, 0, stream>>>(
            qb, kb, sc, nullptr, nullptr, nullptr, nullptr,
            128, 512, 512, 256, inv_sqrt_d, NH, SD, DH, SD, DH, 262144, 65536, 0, 0, 0);
        softmax_rows<<<4096, blk, 0, stream>>>(sc);
        // o = q + att @ v
        gemm_k<false, false, false, true, false><<<dim3(1, 2, 64), blk, 0, stream>>>(
            sc, vb, ob, nullptr, qb, nullptr, nullptr,
            256, 256, 512, 512, 1.f, NH, 262144, 65536, SD, DH, SD, DH, SD, DH, 0);
        // h = o + relu(o @ wo + bo)
        gemm_k<false, true, true, true, false><<<dim3(4, 32, 1), blk, 0, stream>>>(
            ob, wo + woff, houts[i], bo + boff, ob, nullptr, nullptr,
            512, 512, 512, 512, 1.f, 1, 0, 0, 0, 0, 0, 0, 0, 0, 0);
        hin = houts[i];
    }

    // ---- stats + z ----
    gemm_k<false, true, false, false, false><<<dim3(1, 32, 1), blk, 0, stream>>>(
        hin, wz, st, bz, nullptr, nullptr, nullptr,
        512, 512, 128, 128, 1.f, 1, 0, 0, 0, 0, 0, 0, 0, 0, 0);
    zgen<<<2560, blk, 0, stream>>>(st, eps, zb);

    // ---- decoder MLP + fused rec_loss, 10 chunks of 4096 rows ----
    for (int c = 0; c < 10; c++) {
        const float* zc = zb + (long)c * 4096 * LD;
        gemm_k<false, true, true, false, false><<<dim3(8, 32, 1), blk, 0, stream>>>(
            zc, w1, d1, b1, nullptr, nullptr, nullptr,
            64, 64, 1024, 1024, 1.f, 1, 0, 0, 0, 0, 0, 0, 0, 0, 0);
        gemm_k<false, true, true, false, false><<<dim3(8, 32, 1), blk, 0, stream>>>(
            d1, w2, d2, b2, nullptr, nullptr, nullptr,
            1024, 1024, 1024, 1024, 1.f, 1, 0, 0, 0, 0, 0, 0, 0, 0, 0);
        gemm_k<false, true, true, false, true><<<dim3(4, 32, 1), blk, 0, stream>>>(
            d2, w3, d1 /*unused*/, b3, nullptr, H, scal + 0,
            1024, 1024, 512, 512, 1.f, 1, 0, 0, 0, 0, 0, 0, 0, 0, c * 4096);
    }

    // ---- EM ----
    em_init<<<16, blk, 0, stream>>>(zb, init_idx, wsf + o_mu, wsf + o_logpi,
                                    wsf + o_musum, wsf + o_NkG);
    for (int it = 0; it < 5; it++) {
        em_step<<<dim3(10, 16), blk, 0, stream>>>(zb, wsf + o_mu, wsf + o_logpi,
                                                  wsf + o_musum, wsf + o_NkG);
        em_update<<<16, 64, 0, stream>>>(wsf + o_mu, wsf + o_logpi,
                                         wsf + o_musum, wsf + o_NkG);
    }

    // ---- KL ----
    kl_kernel<<<dim3(10, 16), blk, 0, stream>>>(zb, st, eps, wsf + o_mu,
                                                wsf + o_logpi, scal + 1);

    finalize<<<1, 64, 0, stream>>>(scal, out);
}

// Round 2
// 1301.353 us; speedup vs baseline: 3.1315x; 3.1315x over previous
//
#include <hip/hip_runtime.h>
#include <hip/hip_bf16.h>
#include <math.h>

// ---------------------------------------------------------------------------
// GMVAE fused pipeline. Round 2: decoder MLP on bf16 MFMA (16x16x32),
// everything feeding EM/KL stays exact fp32.
// B=16 S=256 D=512 H_heads=4 dh=128 L=64 K=20 MC=10 EM_ITERS=5
// ---------------------------------------------------------------------------

#define BATCH 16
#define SEQ 256
#define DIM 512
#define NH 4
#define DH 128
#define LD 64      // latent dim L
#define KC 20      // clusters
#define MC 10
#define NPTS 2560  // S*MC per batch
#define BS_TOT 4096  // B*S
#define NROWS 40960  // B*S*MC
#define LOG_NORM (-0.9189385332046727f)

typedef __attribute__((ext_vector_type(8))) short bf16x8;
typedef __attribute__((ext_vector_type(4))) float f32x4;

__device__ inline float warpReduceSum(float v) {
    for (int o = 32; o > 0; o >>= 1) v += __shfl_down(v, o);
    return v;
}
__device__ inline float warpReduceMax(float v) {
    for (int o = 32; o > 0; o >>= 1) v = fmaxf(v, __shfl_down(v, o));
    return v;
}

__device__ inline void async_copy16(const __hip_bfloat16* g, __hip_bfloat16* l) {
    __builtin_amdgcn_global_load_lds(
        (const __attribute__((address_space(1))) unsigned int*)g,
        (__attribute__((address_space(3))) unsigned int*)l, 16, 0, 0);
}

// ---------------------------------------------------------------------------
// fp32 tiled GEMM (unchanged from round 1) — still used for the MAB path.
// ---------------------------------------------------------------------------
template<bool TRANS_B, bool HAS_BIAS, bool RELU, bool RESID, bool SQLOSS>
__global__ __launch_bounds__(256)
void gemm_k(const float* __restrict__ A, const float* __restrict__ Bm,
            float* __restrict__ C,
            const float* __restrict__ bias,
            const float* __restrict__ R,
            const float* __restrict__ Href,
            float* __restrict__ lossAcc,
            int K, int lda, int ldb, int ldc,
            float alpha, int nh,
            long aSB, long aSH, long bSB, long bSH,
            long cSB, long cSH, long rSB, long rSH,
            int mOffset)
{
    __shared__ float As[16][132];
    __shared__ float Bs[16][132];
    __shared__ float redS[4];

    const int t = threadIdx.x;
    const int bz = blockIdx.z;
    const int bb = bz / nh, hh = bz % nh;
    A += bb * aSB + hh * aSH;
    Bm += bb * bSB + hh * bSH;
    C += bb * cSB + hh * cSH;
    if (RESID) R += bb * rSB + hh * rSH;

    const int m0g = blockIdx.y * 128;
    const int n0g = blockIdx.x * 128;
    const int tx = t & 15, ty = t >> 4;

    float acc[8][8];
#pragma unroll
    for (int i = 0; i < 8; i++)
#pragma unroll
        for (int j = 0; j < 8; j++) acc[i][j] = 0.f;

    const int nkt = K >> 4;
    for (int kt = 0; kt < nkt; ++kt) {
#pragma unroll
        for (int p = 0; p < 2; p++) {
            int fidx = t + p * 256;
            int row = fidx >> 2, c4 = fidx & 3;
            const float4 av = *(const float4*)&A[(long)(m0g + row) * lda + kt * 16 + c4 * 4];
            As[c4 * 4 + 0][row] = av.x;
            As[c4 * 4 + 1][row] = av.y;
            As[c4 * 4 + 2][row] = av.z;
            As[c4 * 4 + 3][row] = av.w;
        }
        if (!TRANS_B) {
#pragma unroll
            for (int p = 0; p < 2; p++) {
                int fidx = t + p * 256;
                int kk = fidx >> 5, c4 = fidx & 31;
                const float4 bv = *(const float4*)&Bm[(long)(kt * 16 + kk) * ldb + n0g + c4 * 4];
                *(float4*)&Bs[kk][c4 * 4] = bv;
            }
        } else {
#pragma unroll
            for (int p = 0; p < 2; p++) {
                int fidx = t + p * 256;
                int row = fidx >> 2, c4 = fidx & 3;
                const float4 bv = *(const float4*)&Bm[(long)(n0g + row) * ldb + kt * 16 + c4 * 4];
                Bs[c4 * 4 + 0][row] = bv.x;
                Bs[c4 * 4 + 1][row] = bv.y;
                Bs[c4 * 4 + 2][row] = bv.z;
                Bs[c4 * 4 + 3][row] = bv.w;
            }
        }
        __syncthreads();
#pragma unroll
        for (int k = 0; k < 16; k++) {
            float a[8], b[8];
            *(float4*)&a[0] = *(const float4*)&As[k][ty * 8];
            *(float4*)&a[4] = *(const float4*)&As[k][ty * 8 + 4];
            *(float4*)&b[0] = *(const float4*)&Bs[k][tx * 8];
            *(float4*)&b[4] = *(const float4*)&Bs[k][tx * 8 + 4];
#pragma unroll
            for (int i = 0; i < 8; i++)
#pragma unroll
                for (int j = 0; j < 8; j++)
                    acc[i][j] = fmaf(a[i], b[j], acc[i][j]);
        }
        __syncthreads();
    }

    float lsum = 0.f;
#pragma unroll
    for (int i = 0; i < 8; i++) {
        const int mg = m0g + ty * 8 + i;
        float v[8];
#pragma unroll
        for (int j = 0; j < 8; j++) {
            const int ng = n0g + tx * 8 + j;
            float x = alpha * acc[i][j];
            if (HAS_BIAS) x += bias[ng];
            if (RELU) x = fmaxf(x, 0.f);
            if (RESID) x += R[(long)mg * ldc + ng];
            if (SQLOSS) {
                const float d = x - Href[(long)((mOffset + mg) / MC) * DIM + ng];
                lsum = fmaf(d, d, lsum);
            }
            v[j] = x;
        }
        if (!SQLOSS) {
            *(float4*)&C[(long)mg * ldc + n0g + tx * 8] = *(float4*)&v[0];
            *(float4*)&C[(long)mg * ldc + n0g + tx * 8 + 4] = *(float4*)&v[4];
        }
    }
    if (SQLOSS) {
        lsum = warpReduceSum(lsum);
        if ((t & 63) == 0) redS[t >> 6] = lsum;
        __syncthreads();
        if (t == 0) atomicAdd(lossAcc, redS[0] + redS[1] + redS[2] + redS[3]);
    }
}

// ---------------------------------------------------------------------------
// bf16 MFMA GEMM for the decoder.  C = relu(A @ BT^T + bias), A: MxK bf16
// row-major, BT: NxK bf16 row-major (pre-transposed weight).  128x128 tile,
// BK=32, 4 waves each computing a 64x64 sub-tile as 4x4 MFMAs of 16x16x32.
// Staging via global_load_lds width=16 (m97 recipe).  SQLOSS: fused
// squared-diff vs Href instead of store (decoder layer 3).
// ---------------------------------------------------------------------------
template<bool SQLOSS>
__global__ __launch_bounds__(256, 2)
void gemm_mfma(const __hip_bfloat16* __restrict__ A,
               const __hip_bfloat16* __restrict__ BT,
               __hip_bfloat16* __restrict__ C,
               const float* __restrict__ bias,
               const float* __restrict__ Href,
               float* __restrict__ lossAcc,
               int K, int N, int rowOffset)
{
    __shared__ __align__(16) __hip_bfloat16 As[128 * 32];
    __shared__ __align__(16) __hip_bfloat16 Bs[128 * 32];
    __shared__ float redS[4];

    const int t = threadIdx.x;
    const int m0 = blockIdx.y * 128, n0 = blockIdx.x * 128;
    const int w = t >> 6, lane = t & 63;
    const int wm = (w >> 1) * 64, wn = (w & 1) * 64;
    const int fm = lane & 15;           // fragment row/col within 16
    const int fk = (lane >> 4) * 8;     // fragment k offset
    const int srow = t >> 2, scol = (t & 3) * 8;  // staging row / k-element

    f32x4 acc[4][4];
#pragma unroll
    for (int i = 0; i < 4; i++)
#pragma unroll
        for (int j = 0; j < 4; j++) acc[i][j] = (f32x4){0.f, 0.f, 0.f, 0.f};

    __hip_bfloat16* la = As + w * 512;  // wave-uniform LDS base (elements)
    __hip_bfloat16* lb = Bs + w * 512;

    const int nkt = K >> 5;
    for (int kt = 0; kt < nkt; kt++) {
        const __hip_bfloat16* ga = A + (long)(m0 + srow) * K + kt * 32 + scol;
        const __hip_bfloat16* gb = BT + (long)(n0 + srow) * K + kt * 32 + scol;
        async_copy16(ga, la);
        async_copy16(ga + 64L * K, la + 2048);
        async_copy16(gb, lb);
        async_copy16(gb + 64L * K, lb + 2048);
        __syncthreads();

        bf16x8 af[4], bfr[4];
#pragma unroll
        for (int mi = 0; mi < 4; mi++)
            af[mi] = *(const bf16x8*)&As[(wm + mi * 16 + fm) * 32 + fk];
#pragma unroll
        for (int ni = 0; ni < 4; ni++)
            bfr[ni] = *(const bf16x8*)&Bs[(wn + ni * 16 + fm) * 32 + fk];
#pragma unroll
        for (int mi = 0; mi < 4; mi++)
#pragma unroll
            for (int ni = 0; ni < 4; ni++)
                acc[mi][ni] = __builtin_amdgcn_mfma_f32_16x16x32_bf16(
                    af[mi], bfr[ni], acc[mi][ni], 0, 0, 0);
        __syncthreads();
    }

    // epilogue: C/D layout col = lane&15, row = (lane>>4)*4 + r
    float lsum = 0.f;
#pragma unroll
    for (int ni = 0; ni < 4; ni++) {
        const int col = n0 + wn + ni * 16 + fm;
        const float b = bias[col];
#pragma unroll
        for (int mi = 0; mi < 4; mi++) {
#pragma unroll
            for (int r = 0; r < 4; r++) {
                const int row = m0 + wm + mi * 16 + (lane >> 4) * 4 + r;
                float x = acc[mi][ni][r] + b;
                x = fmaxf(x, 0.f);
                if (SQLOSS) {
                    const float d = x - Href[(long)((rowOffset + row) / MC) * DIM + col];
                    lsum = fmaf(d, d, lsum);
                } else {
                    C[(long)row * N + col] = __float2bfloat16(x);
                }
            }
        }
    }
    if (SQLOSS) {
        lsum = warpReduceSum(lsum);
        if (lane == 0) redS[w] = lsum;
        __syncthreads();
        if (t == 0) atomicAdd(lossAcc, redS[0] + redS[1] + redS[2] + redS[3]);
    }
}

// ---------------------------------------------------------------------------
// weight transpose + bf16 convert: w (KxN fp32, row-major) -> wT (NxK bf16)
// ---------------------------------------------------------------------------
__global__ void convert_wT(const float* __restrict__ w, __hip_bfloat16* __restrict__ wT,
                           int K, int N)
{
    const int idx = blockIdx.x * 256 + threadIdx.x;
    if (idx < K * N) {
        const int k = idx / N, n = idx % N;
        wT[(long)n * K + k] = __float2bfloat16(w[idx]);
    }
}

// ---------------------------------------------------------------------------
__global__ __launch_bounds__(256)
void softmax_rows(float* __restrict__ S)
{
    const long row = (long)blockIdx.x * 4 + (threadIdx.x >> 6);
    const int lane = threadIdx.x & 63;
    float4 v = *(float4*)&S[row * 256 + lane * 4];
    float mx = fmaxf(fmaxf(v.x, v.y), fmaxf(v.z, v.w));
    mx = warpReduceMax(mx);
    mx = __shfl(mx, 0);
    v.x = expf(v.x - mx); v.y = expf(v.y - mx);
    v.z = expf(v.z - mx); v.w = expf(v.w - mx);
    float s = v.x + v.y + v.z + v.w;
    s = warpReduceSum(s);
    s = __shfl(s, 0);
    const float inv = 1.f / s;
    v.x *= inv; v.y *= inv; v.z *= inv; v.w *= inv;
    *(float4*)&S[row * 256 + lane * 4] = v;
}

// ---------------------------------------------------------------------------
// z = mean + eps*exp(0.5*logvar); also emits bf16 copy for the decoder.
// ---------------------------------------------------------------------------
__global__ __launch_bounds__(256)
void zgen(const float* __restrict__ stats, const float* __restrict__ eps,
          float* __restrict__ z, __hip_bfloat16* __restrict__ z16)
{
    const int idx = blockIdx.x * 256 + threadIdx.x;  // float4 index
    const int bs = idx / 160;
    const int r = idx % 160;
    const int l4 = r % 16;
    const float4 e = ((const float4*)eps)[idx];
    const float4 mn = ((const float4*)stats)[bs * 32 + l4];
    const float4 lv = ((const float4*)stats)[bs * 32 + 16 + l4];
    float4 zz;
    zz.x = fmaf(e.x, expf(0.5f * lv.x), mn.x);
    zz.y = fmaf(e.y, expf(0.5f * lv.y), mn.y);
    zz.z = fmaf(e.z, expf(0.5f * lv.z), mn.z);
    zz.w = fmaf(e.w, expf(0.5f * lv.w), mn.w);
    ((float4*)z)[idx] = zz;
    __hip_bfloat16* zp = z16 + (long)idx * 4;
    zp[0] = __float2bfloat16(zz.x);
    zp[1] = __float2bfloat16(zz.y);
    zp[2] = __float2bfloat16(zz.z);
    zp[3] = __float2bfloat16(zz.w);
}

// ---------------------------------------------------------------------------
__global__ void em_init(const float* __restrict__ z, const int* __restrict__ init_idx,
                        float* __restrict__ mu, float* __restrict__ logPi,
                        float* __restrict__ musum, float* __restrict__ NkG)
{
    const int b = blockIdx.x, t = threadIdx.x;
    for (int i = t; i < KC * LD; i += 256) {
        const int k = i >> 6, l = i & 63;
        const int idx = init_idx[b * KC + k];
        mu[b * KC * LD + i] = z[((long)b * NPTS + idx) * LD + l];
        musum[b * KC * LD + i] = 0.f;
    }
    if (t < KC) {
        logPi[b * KC + t] = -logf((float)KC);
        NkG[b * KC + t] = 0.f;
    }
}

__global__ __launch_bounds__(256)
void em_step(const float* __restrict__ z, const float* __restrict__ mu,
             const float* __restrict__ logPi,
             float* __restrict__ musum, float* __restrict__ NkG)
{
    __shared__ float muS[KC][65];
    __shared__ float m2lp[KC];
    __shared__ float postS[KC][256];
    __shared__ float NkS[KC];

    const int tile = blockIdx.x, b = blockIdx.y, t = threadIdx.x;

    for (int i = t; i < KC * LD; i += 256) muS[i >> 6][i & 63] = mu[b * KC * LD + i];
    __syncthreads();
    if (t < KC) {
        float s = 0.f;
        for (int l = 0; l < LD; l++) { const float m = muS[t][l]; s = fmaf(m, m, s); }
        m2lp[t] = -0.5f * s + logPi[b * KC + t];
    }
    __syncthreads();

    const long n = (long)tile * 256 + t;
    const float* zr = &z[((long)b * NPTS + n) * LD];
    float acc[KC];
#pragma unroll
    for (int k = 0; k < KC; k++) acc[k] = 0.f;
#pragma unroll
    for (int l4 = 0; l4 < 16; l4++) {
        const float4 zv = ((const float4*)zr)[l4];
#pragma unroll
        for (int k = 0; k < KC; k++) {
            acc[k] = fmaf(zv.x, muS[k][l4 * 4 + 0], acc[k]);
            acc[k] = fmaf(zv.y, muS[k][l4 * 4 + 1], acc[k]);
            acc[k] = fmaf(zv.z, muS[k][l4 * 4 + 2], acc[k]);
            acc[k] = fmaf(zv.w, muS[k][l4 * 4 + 3], acc[k]);
        }
    }
    float mx = -1e30f;
    float llv[KC];
#pragma unroll
    for (int k = 0; k < KC; k++) { llv[k] = acc[k] + m2lp[k]; mx = fmaxf(mx, llv[k]); }
    float s = 0.f;
#pragma unroll
    for (int k = 0; k < KC; k++) { llv[k] = expf(llv[k] - mx); s += llv[k]; }
    const float inv = 1.f / s;
#pragma unroll
    for (int k = 0; k < KC; k++) postS[k][t] = llv[k] * inv;
    __syncthreads();

    const int lane = t & 63, w = t >> 6;
#pragma unroll
    for (int kk = 0; kk < 5; kk++) {
        const int k = w * 5 + kk;
        float p = postS[k][lane] + postS[k][lane + 64] + postS[k][lane + 128] + postS[k][lane + 192];
        p = warpReduceSum(p);
        if (lane == 0) NkS[k] = p;
    }
    __syncthreads();

    const float* zb = &z[((long)b * NPTS + (long)tile * 256) * LD];
#pragma unroll
    for (int j = 0; j < 5; j++) {
        const int o = t + j * 256;
        const int k = o >> 6, l = o & 63;
        float sacc = 0.f;
        for (int n2 = 0; n2 < 256; n2++)
            sacc = fmaf(postS[k][n2], zb[n2 * LD + l], sacc);
        atomicAdd(&musum[b * KC * LD + o], sacc);
    }
    if (t < KC) atomicAdd(&NkG[b * KC + t], NkS[t]);
}

__global__ void em_update(float* __restrict__ mu, float* __restrict__ logPi,
                          float* __restrict__ musum, float* __restrict__ NkG)
{
    __shared__ float Nk[KC];
    const int b = blockIdx.x, t = threadIdx.x;
    if (t < KC) Nk[t] = NkG[b * KC + t];
    __syncthreads();
    float s = 0.f;
    for (int k = 0; k < KC; k++) s += Nk[k];
    if (t < KC) logPi[b * KC + t] = logf(Nk[t] / s);
    for (int i = t; i < KC * LD; i += 64) {
        const int k = i >> 6;
        mu[b * KC * LD + i] = musum[b * KC * LD + i] / Nk[k];
        musum[b * KC * LD + i] = 0.f;
    }
    __syncthreads();
    if (t < KC) NkG[b * KC + t] = 0.f;
}

__global__ __launch_bounds__(256)
void kl_kernel(const float* __restrict__ z, const float* __restrict__ stats,
               const float* __restrict__ eps,
               const float* __restrict__ mu, const float* __restrict__ logPi,
               float* __restrict__ klAcc)
{
    __shared__ float muS[KC][65];
    __shared__ float m2lp[KC];
    __shared__ float redS[4];

    const int tile = blockIdx.x, b = blockIdx.y, t = threadIdx.x;

    for (int i = t; i < KC * LD; i += 256) muS[i >> 6][i & 63] = mu[b * KC * LD + i];
    __syncthreads();
    if (t < KC) {
        float s = 0.f;
        for (int l = 0; l < LD; l++) { const float m = muS[t][l]; s = fmaf(m, m, s); }
        m2lp[t] = -0.5f * s + logPi[b * KC + t];
    }
    __syncthreads();

    const int n = tile * 256 + t;
    const int sidx = n / MC, m = n % MC;
    const long bs = (long)b * SEQ + sidx;
    const float* zr = &z[((long)b * NPTS + n) * LD];

    float acc[KC];
#pragma unroll
    for (int k = 0; k < KC; k++) acc[k] = 0.f;
    float x2 = 0.f;
#pragma unroll
    for (int l4 = 0; l4 < 16; l4++) {
        const float4 zv = ((const float4*)zr)[l4];
        x2 = fmaf(zv.x, zv.x, fmaf(zv.y, zv.y, fmaf(zv.z, zv.z, fmaf(zv.w, zv.w, x2))));
#pragma unroll
        for (int k = 0; k < KC; k++) {
            acc[k] = fmaf(zv.x, muS[k][l4 * 4 + 0], acc[k]);
            acc[k] = fmaf(zv.y, muS[k][l4 * 4 + 1], acc[k]);
            acc[k] = fmaf(zv.z, muS[k][l4 * 4 + 2], acc[k]);
            acc[k] = fmaf(zv.w, muS[k][l4 * 4 + 3], acc[k]);
        }
    }
    float mx = -1e30f;
    float llv[KC];
#pragma unroll
    for (int k = 0; k < KC; k++) { llv[k] = acc[k] + m2lp[k]; mx = fmaxf(mx, llv[k]); }
    float s = 0.f;
#pragma unroll
    for (int k = 0; k < KC; k++) s += expf(llv[k] - mx);
    const float log_pz = -0.5f * x2 + mx + logf(s) + LD * LOG_NORM;

    const float* lvr = &stats[bs * 128 + 64];
    const float* er = &eps[(bs * MC + m) * LD];
    float slv = 0.f, se2 = 0.f;
#pragma unroll
    for (int l4 = 0; l4 < 16; l4++) {
        const float4 lv = ((const float4*)lvr)[l4];
        slv += lv.x + lv.y + lv.z + lv.w;
        const float4 e = ((const float4*)er)[l4];
        se2 = fmaf(e.x, e.x, fmaf(e.y, e.y, fmaf(e.z, e.z, fmaf(e.w, e.w, se2))));
    }
    const float log_qz = -0.5f * (slv + se2) + LD * LOG_NORM;

    float v = log_qz - log_pz;
    v = warpReduceSum(v);
    if ((t & 63) == 0) redS[t >> 6] = v;
    __syncthreads();
    if (t == 0) atomicAdd(klAcc, redS[0] + redS[1] + redS[2] + redS[3]);
}

__global__ void finalize(const float* __restrict__ scal, float* __restrict__ out)
{
    if (threadIdx.x == 0) {
        out[0] = scal[0] * (1.f / (float)NROWS);
        out[1] = scal[1] * (1.f / (float)NROWS);
    }
}

// ---------------------------------------------------------------------------
extern "C" void kernel_launch(void* const* d_in, const int* in_sizes, int n_in,
                              void* d_out, int out_size, void* d_ws, size_t ws_size,
                              hipStream_t stream)
{
    const float* H   = (const float*)d_in[0];
    const float* eps = (const float*)d_in[1];
    const float* wq  = (const float*)d_in[2];
    const float* bq  = (const float*)d_in[3];
    const float* wk  = (const float*)d_in[4];
    const float* bk  = (const float*)d_in[5];
    const float* wv  = (const float*)d_in[6];
    const float* bv  = (const float*)d_in[7];
    const float* wo  = (const float*)d_in[8];
    const float* bo  = (const float*)d_in[9];
    const float* wz  = (const float*)d_in[10];
    const float* bz  = (const float*)d_in[11];
    const float* w1  = (const float*)d_in[12];
    const float* b1  = (const float*)d_in[13];
    const float* w2  = (const float*)d_in[14];
    const float* b2  = (const float*)d_in[15];
    const float* w3  = (const float*)d_in[16];
    const float* b3  = (const float*)d_in[17];
    const int* init_idx = (const int*)d_in[18];
    float* out = (float*)d_out;
    float* wsf = (float*)d_ws;

    // ws layout (float offsets); stays within the proven ~80 MB footprint.
    const long o_scal  = 0;
    const long o_NkG   = 1024;
    const long o_musum = 2048;
    const long o_logpi = 23552;
    const long o_mu    = 24576;
    const long o_q     = 45056;
    const long o_k     = o_q  + 2097152;
    const long o_v     = o_k  + 2097152;
    const long o_o     = o_v  + 2097152;
    const long o_hA    = o_o  + 2097152;
    const long o_hB    = o_hA + 2097152;
    const long o_sc    = o_hB + 2097152;          // scores 4194304
    const long o_stats = o_sc + 4194304;          // 524288
    const long o_z     = o_stats + 524288;        // 2621440  (end ~19.97M floats)
    // decoder-phase overlays (q..sc region is dead after zgen):
    const long o_z16   = o_q;                     // 2.62M bf16 = 1310720 float slots
    const long o_d1    = o_q + 1310720;           // 10240x1024 bf16 = 5242880 slots
    const long o_d2    = o_d1 + 5242880;
    // weight-transpose overlays (sc region, dead after MAB2):
    const long o_w1T   = o_sc;                    // 1024x64  bf16 = 32768 slots
    const long o_w2T   = o_sc + 32768;            // 1024x1024 bf16 = 524288 slots
    const long o_w3T   = o_w2T + 524288;          // 512x1024 bf16 = 262144 slots

    float* qb = wsf + o_q;  float* kb = wsf + o_k;  float* vb = wsf + o_v;
    float* ob = wsf + o_o;  float* hA = wsf + o_hA; float* hB = wsf + o_hB;
    float* sc = wsf + o_sc; float* st = wsf + o_stats; float* zb = wsf + o_z;
    float* scal = wsf + o_scal;
    __hip_bfloat16* z16 = (__hip_bfloat16*)(wsf + o_z16);
    __hip_bfloat16* d1  = (__hip_bfloat16*)(wsf + o_d1);
    __hip_bfloat16* d2  = (__hip_bfloat16*)(wsf + o_d2);
    __hip_bfloat16* w1T = (__hip_bfloat16*)(wsf + o_w1T);
    __hip_bfloat16* w2T = (__hip_bfloat16*)(wsf + o_w2T);
    __hip_bfloat16* w3T = (__hip_bfloat16*)(wsf + o_w3T);

    hipMemsetAsync(scal, 0, 64, stream);

    const dim3 blk(256);
    const long SD = (long)SEQ * DIM;
    const float inv_sqrt_d = 0.044194173824159216f;

    // ---- 2x MAB (fp32, exact) ----
    const float* hin = H;
    float* houts[2] = { hA, hB };
    for (int i = 0; i < 2; i++) {
        const long woff = (long)i * DIM * DIM, boff = (long)i * DIM;
        gemm_k<false, true, false, false, false><<<dim3(4, 32, 1), blk, 0, stream>>>(
            hin, wq + woff, qb, bq + boff, nullptr, nullptr, nullptr,
            512, 512, 512, 512, 1.f, 1, 0, 0, 0, 0, 0, 0, 0, 0, 0);
        gemm_k<false, true, false, false, false><<<dim3(4, 32, 1), blk, 0, stream>>>(
            hin, wk + woff, kb, bk + boff, nullptr, nullptr, nullptr,
            512, 512, 512, 512, 1.f, 1, 0, 0, 0, 0, 0, 0, 0, 0, 0);
        gemm_k<false, true, false, false, false><<<dim3(4, 32, 1), blk, 0, stream>>>(
            hin, wv + woff, vb, bv + boff, nullptr, nullptr, nullptr,
            512, 512, 512, 512, 1.f, 1, 0, 0, 0, 0, 0, 0, 0, 0, 0);
        gemm_k<true, false, false, false, false><<<dim3(2, 2, 64), blk, 0, stream>>>(
            qb, kb, sc, nullptr, nullptr, nullptr, nullptr,
            128, 512, 512, 256, inv_sqrt_d, NH, SD, DH, SD, DH, 262144, 65536, 0, 0, 0);
        softmax_rows<<<4096, blk, 0, stream>>>(sc);
        gemm_k<false, false, false, true, false><<<dim3(1, 2, 64), blk, 0, stream>>>(
            sc, vb, ob, nullptr, qb, nullptr, nullptr,
            256, 256, 512, 512, 1.f, NH, 262144, 65536, SD, DH, SD, DH, SD, DH, 0);
        gemm_k<false, true, true, true, false><<<dim3(4, 32, 1), blk, 0, stream>>>(
            ob, wo + woff, houts[i], bo + boff, ob, nullptr, nullptr,
            512, 512, 512, 512, 1.f, 1, 0, 0, 0, 0, 0, 0, 0, 0, 0);
        hin = houts[i];
    }

    // ---- stats + z (fp32 exact; bf16 copy of z for the decoder) ----
    gemm_k<false, true, false, false, false><<<dim3(1, 32, 1), blk, 0, stream>>>(
        hin, wz, st, bz, nullptr, nullptr, nullptr,
        512, 512, 128, 128, 1.f, 1, 0, 0, 0, 0, 0, 0, 0, 0, 0);
    zgen<<<2560, blk, 0, stream>>>(st, eps, zb, z16);

    // ---- weight transpose+convert (sc region is dead now) ----
    convert_wT<<<(64 * 1024 + 255) / 256, blk, 0, stream>>>(w1, w1T, 64, 1024);
    convert_wT<<<(1024 * 1024 + 255) / 256, blk, 0, stream>>>(w2, w2T, 1024, 1024);
    convert_wT<<<(1024 * 512 + 255) / 256, blk, 0, stream>>>(w3, w3T, 1024, 512);

    // ---- decoder MLP on MFMA + fused rec_loss, 4 chunks of 10240 rows ----
    for (int c = 0; c < 4; c++) {
        const long rows0 = (long)c * 10240;
        gemm_mfma<false><<<dim3(8, 80), blk, 0, stream>>>(
            z16 + rows0 * LD, w1T, d1, b1, nullptr, nullptr, 64, 1024, 0);
        gemm_mfma<false><<<dim3(8, 80), blk, 0, stream>>>(
            d1, w2T, d2, b2, nullptr, nullptr, 1024, 1024, 0);
        gemm_mfma<true><<<dim3(4, 80), blk, 0, stream>>>(
            d2, w3T, nullptr, b3, H, scal + 0, 1024, 512, (int)rows0);
    }

    // ---- EM (fp32, exact) ----
    em_init<<<16, blk, 0, stream>>>(zb, init_idx, wsf + o_mu, wsf + o_logpi,
                                    wsf + o_musum, wsf + o_NkG);
    for (int it = 0; it < 5; it++) {
        em_step<<<dim3(10, 16), blk, 0, stream>>>(zb, wsf + o_mu, wsf + o_logpi,
                                                  wsf + o_musum, wsf + o_NkG);
        em_update<<<16, 64, 0, stream>>>(wsf + o_mu, wsf + o_logpi,
                                         wsf + o_musum, wsf + o_NkG);
    }

    // ---- KL (fp32, exact) ----
    kl_kernel<<<dim3(10, 16), blk, 0, stream>>>(zb, st, eps, wsf + o_mu,
                                                wsf + o_logpi, scal + 1);

    finalize<<<1, 64, 0, stream>>>(scal, out);
}

// Round 3
// 941.489 us; speedup vs baseline: 4.3285x; 1.3822x over previous
//
#include <hip/hip_runtime.h>
#include <hip/hip_bf16.h>
#include <math.h>

// ---------------------------------------------------------------------------
// GMVAE fused pipeline. Round 3: MAB/stats GEMMs on split-bf16 (hi/lo) MFMA
// = fp32-equivalent accuracy (error ~2^-18) at matrix-core rate.
// Decoder stays plain bf16 MFMA. EM/KL/zgen exact fp32.
// B=16 S=256 D=512 H_heads=4 dh=128 L=64 K=20 MC=10 EM_ITERS=5
// ---------------------------------------------------------------------------

#define BATCH 16
#define SEQ 256
#define DIM 512
#define NH 4
#define DH 128
#define LD 64
#define KC 20
#define MC 10
#define NPTS 2560
#define BS_TOT 4096
#define NROWS 40960
#define LOG_NORM (-0.9189385332046727f)

typedef __attribute__((ext_vector_type(8))) short bf16x8;
typedef __attribute__((ext_vector_type(4))) float f32x4;

__device__ inline float warpReduceSum(float v) {
    for (int o = 32; o > 0; o >>= 1) v += __shfl_down(v, o);
    return v;
}
__device__ inline float warpReduceMax(float v) {
    for (int o = 32; o > 0; o >>= 1) v = fmaxf(v, __shfl_down(v, o));
    return v;
}

__device__ inline void async_copy16(const __hip_bfloat16* g, __hip_bfloat16* l) {
    __builtin_amdgcn_global_load_lds(
        (const __attribute__((address_space(1))) unsigned int*)g,
        (__attribute__((address_space(3))) unsigned int*)l, 16, 0, 0);
}

__device__ inline void split_store(float x, __hip_bfloat16* ph, __hip_bfloat16* pl, long idx) {
    const __hip_bfloat16 h = __float2bfloat16(x);
    ph[idx] = h;
    pl[idx] = __float2bfloat16(x - __bfloat162float(h));
}

// ---------------------------------------------------------------------------
// Split-bf16 MFMA GEMM: C = A @ BT^T computed as Ah·Bh + Ah·Bl + Al·Bh
// (fp32-equivalent). 128x128 tile, BK=32, 4 waves x (4x4) 16x16x32 MFMAs.
// MODE: 0=QKV(fused q/k/vT out) 1=SCORES(fp32 out *alpha) 2=PV(+q resid, o out)
//       3=OPROJ(bias,relu,+o resid, h out) 4=STATS(fp32 out +bias)
// ---------------------------------------------------------------------------
template<int MODE>
__global__ __launch_bounds__(256, 2)
void gemm3(const __hip_bfloat16* __restrict__ Ah, const __hip_bfloat16* __restrict__ Al,
           const __hip_bfloat16* __restrict__ Bh, const __hip_bfloat16* __restrict__ Bl,
           int K, int lda, int ldb,
           long aZb, long aZh, long bZb, long bZh,
           const float* __restrict__ b0, const float* __restrict__ b1v,
           const float* __restrict__ b2v,
           float alpha, float* __restrict__ outF,
           __hip_bfloat16* __restrict__ P1h, __hip_bfloat16* __restrict__ P1l,
           __hip_bfloat16* __restrict__ P2h, __hip_bfloat16* __restrict__ P2l,
           __hip_bfloat16* __restrict__ P3h, __hip_bfloat16* __restrict__ P3l,
           const __hip_bfloat16* __restrict__ Rh, const __hip_bfloat16* __restrict__ Rl)
{
    __shared__ __align__(16) __hip_bfloat16 As[128 * 32];
    __shared__ __align__(16) __hip_bfloat16 Bs[128 * 32];

    const int t = threadIdx.x;
    const int z = blockIdx.z;
    const int zb_ = z >> 2, zh_ = z & 3;
    const long aOff = (long)zb_ * aZb + (long)zh_ * aZh;
    const long bOff = (long)zb_ * bZb + (long)zh_ * bZh;

    const int m0 = blockIdx.y * 128, n0 = blockIdx.x * 128;
    const int w = t >> 6, lane = t & 63;
    const int wm = (w >> 1) * 64, wn = (w & 1) * 64;
    const int fm = lane & 15;
    const int fk = (lane >> 4) * 8;
    const int srow = t >> 2, scol = (t & 3) * 8;

    f32x4 acc[4][4];
#pragma unroll
    for (int i = 0; i < 4; i++)
#pragma unroll
        for (int j = 0; j < 4; j++) acc[i][j] = (f32x4){0.f, 0.f, 0.f, 0.f};

    __hip_bfloat16* la = As + w * 512;
    __hip_bfloat16* lb = Bs + w * 512;

    const int nk = K >> 5;
    for (int ph = 0; ph < 3; ph++) {
        const __hip_bfloat16* pA = ((ph == 2) ? Al : Ah) + aOff;
        const __hip_bfloat16* pB = ((ph == 1) ? Bl : Bh) + bOff;
        for (int kk = 0; kk < nk; kk++) {
            const __hip_bfloat16* ga = pA + (long)(m0 + srow) * lda + kk * 32 + scol;
            const __hip_bfloat16* gb = pB + (long)(n0 + srow) * ldb + kk * 32 + scol;
            async_copy16(ga, la);
            async_copy16(ga + 64L * lda, la + 2048);
            async_copy16(gb, lb);
            async_copy16(gb + 64L * ldb, lb + 2048);
            __syncthreads();

            bf16x8 af[4], bfr[4];
#pragma unroll
            for (int mi = 0; mi < 4; mi++)
                af[mi] = *(const bf16x8*)&As[(wm + mi * 16 + fm) * 32 + fk];
#pragma unroll
            for (int ni = 0; ni < 4; ni++)
                bfr[ni] = *(const bf16x8*)&Bs[(wn + ni * 16 + fm) * 32 + fk];
#pragma unroll
            for (int mi = 0; mi < 4; mi++)
#pragma unroll
                for (int ni = 0; ni < 4; ni++)
                    acc[mi][ni] = __builtin_amdgcn_mfma_f32_16x16x32_bf16(
                        af[mi], bfr[ni], acc[mi][ni], 0, 0, 0);
            __syncthreads();
        }
    }

    // epilogue: C/D layout col = lane&15 (within 16), row = (lane>>4)*4 + r
#pragma unroll
    for (int ni = 0; ni < 4; ni++) {
        const int col = n0 + wn + ni * 16 + fm;
#pragma unroll
        for (int mi = 0; mi < 4; mi++) {
#pragma unroll
            for (int r = 0; r < 4; r++) {
                const int row = m0 + wm + mi * 16 + (lane >> 4) * 4 + r;
                float x = acc[mi][ni][r];
                if (MODE == 0) {  // QKV fused: which 512-range of N=1536
                    const int which = n0 >> 9;
                    const int colq = col & 511;
                    if (which == 0) {
                        x += b0[colq];
                        split_store(x, P1h, P1l, (long)row * 512 + colq);
                    } else if (which == 1) {
                        x += b1v[colq];
                        split_store(x, P2h, P2l, (long)row * 512 + colq);
                    } else {  // v, written transposed per head: [b][h][d][s]
                        x += b2v[colq];
                        const int bb = row >> 8, s = row & 255;
                        const int hh = colq >> 7, dd = colq & 127;
                        const long idx = (((long)(bb * NH + hh) * DH + dd) * SEQ) + s;
                        split_store(x, P3h, P3l, idx);
                    }
                } else if (MODE == 1) {  // SCORES fp32 out
                    outF[(long)z * 65536 + (long)row * 256 + col] = x * alpha;
                } else if (MODE == 2) {  // PV: o = q + att@v
                    const long idx = ((long)(zb_ * 256 + row)) * 512 + zh_ * 128 + col;
                    x += __bfloat162float(Rh[idx]) + __bfloat162float(Rl[idx]);
                    split_store(x, P1h, P1l, idx);
                } else if (MODE == 3) {  // OPROJ: h = o + relu(x + bo)
                    const long idx = (long)row * 512 + col;
                    x = fmaxf(x + b0[col], 0.f);
                    x += __bfloat162float(Rh[idx]) + __bfloat162float(Rl[idx]);
                    split_store(x, P1h, P1l, idx);
                } else {  // STATS fp32 out
                    outF[(long)row * 128 + col] = x + b0[col];
                }
            }
        }
    }
}

// ---------------------------------------------------------------------------
// plain-bf16 MFMA GEMM for the decoder (round-2, verified).
// ---------------------------------------------------------------------------
template<bool SQLOSS>
__global__ __launch_bounds__(256, 2)
void gemm_mfma(const __hip_bfloat16* __restrict__ A,
               const __hip_bfloat16* __restrict__ BT,
               __hip_bfloat16* __restrict__ C,
               const float* __restrict__ bias,
               const float* __restrict__ Href,
               float* __restrict__ lossAcc,
               int K, int N, int rowOffset)
{
    __shared__ __align__(16) __hip_bfloat16 As[128 * 32];
    __shared__ __align__(16) __hip_bfloat16 Bs[128 * 32];
    __shared__ float redS[4];

    const int t = threadIdx.x;
    const int m0 = blockIdx.y * 128, n0 = blockIdx.x * 128;
    const int w = t >> 6, lane = t & 63;
    const int wm = (w >> 1) * 64, wn = (w & 1) * 64;
    const int fm = lane & 15;
    const int fk = (lane >> 4) * 8;
    const int srow = t >> 2, scol = (t & 3) * 8;

    f32x4 acc[4][4];
#pragma unroll
    for (int i = 0; i < 4; i++)
#pragma unroll
        for (int j = 0; j < 4; j++) acc[i][j] = (f32x4){0.f, 0.f, 0.f, 0.f};

    __hip_bfloat16* la = As + w * 512;
    __hip_bfloat16* lb = Bs + w * 512;

    const int nkt = K >> 5;
    for (int kt = 0; kt < nkt; kt++) {
        const __hip_bfloat16* ga = A + (long)(m0 + srow) * K + kt * 32 + scol;
        const __hip_bfloat16* gb = BT + (long)(n0 + srow) * K + kt * 32 + scol;
        async_copy16(ga, la);
        async_copy16(ga + 64L * K, la + 2048);
        async_copy16(gb, lb);
        async_copy16(gb + 64L * K, lb + 2048);
        __syncthreads();

        bf16x8 af[4], bfr[4];
#pragma unroll
        for (int mi = 0; mi < 4; mi++)
            af[mi] = *(const bf16x8*)&As[(wm + mi * 16 + fm) * 32 + fk];
#pragma unroll
        for (int ni = 0; ni < 4; ni++)
            bfr[ni] = *(const bf16x8*)&Bs[(wn + ni * 16 + fm) * 32 + fk];
#pragma unroll
        for (int mi = 0; mi < 4; mi++)
#pragma unroll
            for (int ni = 0; ni < 4; ni++)
                acc[mi][ni] = __builtin_amdgcn_mfma_f32_16x16x32_bf16(
                    af[mi], bfr[ni], acc[mi][ni], 0, 0, 0);
        __syncthreads();
    }

    float lsum = 0.f;
#pragma unroll
    for (int ni = 0; ni < 4; ni++) {
        const int col = n0 + wn + ni * 16 + fm;
        const float b = bias[col];
#pragma unroll
        for (int mi = 0; mi < 4; mi++) {
#pragma unroll
            for (int r = 0; r < 4; r++) {
                const int row = m0 + wm + mi * 16 + (lane >> 4) * 4 + r;
                float x = acc[mi][ni][r] + b;
                x = fmaxf(x, 0.f);
                if (SQLOSS) {
                    const float d = x - Href[(long)((rowOffset + row) / MC) * DIM + col];
                    lsum = fmaf(d, d, lsum);
                } else {
                    C[(long)row * N + col] = __float2bfloat16(x);
                }
            }
        }
    }
    if (SQLOSS) {
        lsum = warpReduceSum(lsum);
        if (lane == 0) redS[w] = lsum;
        __syncthreads();
        if (t == 0) atomicAdd(lossAcc, redS[0] + redS[1] + redS[2] + redS[3]);
    }
}

// ---------------------------------------------------------------------------
// converters
// ---------------------------------------------------------------------------
__global__ void conv_split_flat(const float* __restrict__ src,
                                __hip_bfloat16* __restrict__ dh,
                                __hip_bfloat16* __restrict__ dl, int n)
{
    const int i = blockIdx.x * 256 + threadIdx.x;
    if (i < n) {
        const float x = src[i];
        const __hip_bfloat16 h = __float2bfloat16(x);
        dh[i] = h;
        dl[i] = __float2bfloat16(x - __bfloat162float(h));
    }
}

// src: KxN fp32 row-major -> dst: NxK hi/lo bf16 (transposed)
__global__ void conv_split_T(const float* __restrict__ src,
                             __hip_bfloat16* __restrict__ dh,
                             __hip_bfloat16* __restrict__ dl, int K, int N)
{
    const int i = blockIdx.x * 256 + threadIdx.x;
    if (i < K * N) {
        const int k = i / N, n = i % N;
        const float x = src[i];
        const __hip_bfloat16 h = __float2bfloat16(x);
        dh[(long)n * K + k] = h;
        dl[(long)n * K + k] = __float2bfloat16(x - __bfloat162float(h));
    }
}

__global__ void convert_wT(const float* __restrict__ w, __hip_bfloat16* __restrict__ wT,
                           int K, int N)
{
    const int idx = blockIdx.x * 256 + threadIdx.x;
    if (idx < K * N) {
        const int k = idx / N, n = idx % N;
        wT[(long)n * K + k] = __float2bfloat16(w[idx]);
    }
}

// ---------------------------------------------------------------------------
// softmax over 16384 rows of 256 fp32 scores; rewrites each row IN PLACE as
// [256 bf16 hi | 256 bf16 lo] (same 1 KB footprint) for the split PV GEMM.
// ---------------------------------------------------------------------------
__global__ __launch_bounds__(256)
void softmax_att(float* __restrict__ S)
{
    const long row = (long)blockIdx.x * 4 + (threadIdx.x >> 6);
    const int lane = threadIdx.x & 63;
    float* rp = S + row * 256;
    float4 v = *(float4*)&rp[lane * 4];
    float mx = fmaxf(fmaxf(v.x, v.y), fmaxf(v.z, v.w));
    mx = warpReduceMax(mx);
    mx = __shfl(mx, 0);
    v.x = expf(v.x - mx); v.y = expf(v.y - mx);
    v.z = expf(v.z - mx); v.w = expf(v.w - mx);
    float s = v.x + v.y + v.z + v.w;
    s = warpReduceSum(s);
    s = __shfl(s, 0);
    const float inv = 1.f / s;
    v.x *= inv; v.y *= inv; v.z *= inv; v.w *= inv;
    // in-place hi/lo: all lanes have loaded before any store (reg-resident)
    __hip_bfloat16* ph = (__hip_bfloat16*)rp;          // 256 hi
    __hip_bfloat16* pl = ph + 256;                     // 256 lo
    const float a[4] = {v.x, v.y, v.z, v.w};
#pragma unroll
    for (int j = 0; j < 4; j++) {
        const __hip_bfloat16 h = __float2bfloat16(a[j]);
        ph[lane * 4 + j] = h;
        pl[lane * 4 + j] = __float2bfloat16(a[j] - __bfloat162float(h));
    }
}

// ---------------------------------------------------------------------------
__global__ __launch_bounds__(256)
void zgen(const float* __restrict__ stats, const float* __restrict__ eps,
          float* __restrict__ z, __hip_bfloat16* __restrict__ z16)
{
    const int idx = blockIdx.x * 256 + threadIdx.x;
    const int bs = idx / 160;
    const int r = idx % 160;
    const int l4 = r % 16;
    const float4 e = ((const float4*)eps)[idx];
    const float4 mn = ((const float4*)stats)[bs * 32 + l4];
    const float4 lv = ((const float4*)stats)[bs * 32 + 16 + l4];
    float4 zz;
    zz.x = fmaf(e.x, expf(0.5f * lv.x), mn.x);
    zz.y = fmaf(e.y, expf(0.5f * lv.y), mn.y);
    zz.z = fmaf(e.z, expf(0.5f * lv.z), mn.z);
    zz.w = fmaf(e.w, expf(0.5f * lv.w), mn.w);
    ((float4*)z)[idx] = zz;
    __hip_bfloat16* zp = z16 + (long)idx * 4;
    zp[0] = __float2bfloat16(zz.x);
    zp[1] = __float2bfloat16(zz.y);
    zp[2] = __float2bfloat16(zz.z);
    zp[3] = __float2bfloat16(zz.w);
}

// ---------------------------------------------------------------------------
__global__ void em_init(const float* __restrict__ z, const int* __restrict__ init_idx,
                        float* __restrict__ mu, float* __restrict__ logPi,
                        float* __restrict__ musum, float* __restrict__ NkG)
{
    const int b = blockIdx.x, t = threadIdx.x;
    for (int i = t; i < KC * LD; i += 256) {
        const int k = i >> 6, l = i & 63;
        const int idx = init_idx[b * KC + k];
        mu[b * KC * LD + i] = z[((long)b * NPTS + idx) * LD + l];
        musum[b * KC * LD + i] = 0.f;
    }
    if (t < KC) {
        logPi[b * KC + t] = -logf((float)KC);
        NkG[b * KC + t] = 0.f;
    }
}

__global__ __launch_bounds__(256)
void em_step(const float* __restrict__ z, const float* __restrict__ mu,
             const float* __restrict__ logPi,
             float* __restrict__ musum, float* __restrict__ NkG)
{
    __shared__ float muS[KC][65];
    __shared__ float m2lp[KC];
    __shared__ float postS[KC][256];
    __shared__ float NkS[KC];

    const int tile = blockIdx.x, b = blockIdx.y, t = threadIdx.x;

    for (int i = t; i < KC * LD; i += 256) muS[i >> 6][i & 63] = mu[b * KC * LD + i];
    __syncthreads();
    if (t < KC) {
        float s = 0.f;
        for (int l = 0; l < LD; l++) { const float m = muS[t][l]; s = fmaf(m, m, s); }
        m2lp[t] = -0.5f * s + logPi[b * KC + t];
    }
    __syncthreads();

    const long n = (long)tile * 256 + t;
    const float* zr = &z[((long)b * NPTS + n) * LD];
    float acc[KC];
#pragma unroll
    for (int k = 0; k < KC; k++) acc[k] = 0.f;
#pragma unroll
    for (int l4 = 0; l4 < 16; l4++) {
        const float4 zv = ((const float4*)zr)[l4];
#pragma unroll
        for (int k = 0; k < KC; k++) {
            acc[k] = fmaf(zv.x, muS[k][l4 * 4 + 0], acc[k]);
            acc[k] = fmaf(zv.y, muS[k][l4 * 4 + 1], acc[k]);
            acc[k] = fmaf(zv.z, muS[k][l4 * 4 + 2], acc[k]);
            acc[k] = fmaf(zv.w, muS[k][l4 * 4 + 3], acc[k]);
        }
    }
    float mx = -1e30f;
    float llv[KC];
#pragma unroll
    for (int k = 0; k < KC; k++) { llv[k] = acc[k] + m2lp[k]; mx = fmaxf(mx, llv[k]); }
    float s = 0.f;
#pragma unroll
    for (int k = 0; k < KC; k++) { llv[k] = expf(llv[k] - mx); s += llv[k]; }
    const float inv = 1.f / s;
#pragma unroll
    for (int k = 0; k < KC; k++) postS[k][t] = llv[k] * inv;
    __syncthreads();

    const int lane = t & 63, w = t >> 6;
#pragma unroll
    for (int kk = 0; kk < 5; kk++) {
        const int k = w * 5 + kk;
        float p = postS[k][lane] + postS[k][lane + 64] + postS[k][lane + 128] + postS[k][lane + 192];
        p = warpReduceSum(p);
        if (lane == 0) NkS[k] = p;
    }
    __syncthreads();

    const float* zb = &z[((long)b * NPTS + (long)tile * 256) * LD];
#pragma unroll
    for (int j = 0; j < 5; j++) {
        const int o = t + j * 256;
        const int k = o >> 6, l = o & 63;
        float sacc = 0.f;
        for (int n2 = 0; n2 < 256; n2++)
            sacc = fmaf(postS[k][n2], zb[n2 * LD + l], sacc);
        atomicAdd(&musum[b * KC * LD + o], sacc);
    }
    if (t < KC) atomicAdd(&NkG[b * KC + t], NkS[t]);
}

__global__ void em_update(float* __restrict__ mu, float* __restrict__ logPi,
                          float* __restrict__ musum, float* __restrict__ NkG)
{
    __shared__ float Nk[KC];
    const int b = blockIdx.x, t = threadIdx.x;
    if (t < KC) Nk[t] = NkG[b * KC + t];
    __syncthreads();
    float s = 0.f;
    for (int k = 0; k < KC; k++) s += Nk[k];
    if (t < KC) logPi[b * KC + t] = logf(Nk[t] / s);
    for (int i = t; i < KC * LD; i += 64) {
        const int k = i >> 6;
        mu[b * KC * LD + i] = musum[b * KC * LD + i] / Nk[k];
        musum[b * KC * LD + i] = 0.f;
    }
    __syncthreads();
    if (t < KC) NkG[b * KC + t] = 0.f;
}

__global__ __launch_bounds__(256)
void kl_kernel(const float* __restrict__ z, const float* __restrict__ stats,
               const float* __restrict__ eps,
               const float* __restrict__ mu, const float* __restrict__ logPi,
               float* __restrict__ klAcc)
{
    __shared__ float muS[KC][65];
    __shared__ float m2lp[KC];
    __shared__ float redS[4];

    const int tile = blockIdx.x, b = blockIdx.y, t = threadIdx.x;

    for (int i = t; i < KC * LD; i += 256) muS[i >> 6][i & 63] = mu[b * KC * LD + i];
    __syncthreads();
    if (t < KC) {
        float s = 0.f;
        for (int l = 0; l < LD; l++) { const float m = muS[t][l]; s = fmaf(m, m, s); }
        m2lp[t] = -0.5f * s + logPi[b * KC + t];
    }
    __syncthreads();

    const int n = tile * 256 + t;
    const int sidx = n / MC, m = n % MC;
    const long bs = (long)b * SEQ + sidx;
    const float* zr = &z[((long)b * NPTS + n) * LD];

    float acc[KC];
#pragma unroll
    for (int k = 0; k < KC; k++) acc[k] = 0.f;
    float x2 = 0.f;
#pragma unroll
    for (int l4 = 0; l4 < 16; l4++) {
        const float4 zv = ((const float4*)zr)[l4];
        x2 = fmaf(zv.x, zv.x, fmaf(zv.y, zv.y, fmaf(zv.z, zv.z, fmaf(zv.w, zv.w, x2))));
#pragma unroll
        for (int k = 0; k < KC; k++) {
            acc[k] = fmaf(zv.x, muS[k][l4 * 4 + 0], acc[k]);
            acc[k] = fmaf(zv.y, muS[k][l4 * 4 + 1], acc[k]);
            acc[k] = fmaf(zv.z, muS[k][l4 * 4 + 2], acc[k]);
            acc[k] = fmaf(zv.w, muS[k][l4 * 4 + 3], acc[k]);
        }
    }
    float mx = -1e30f;
    float llv[KC];
#pragma unroll
    for (int k = 0; k < KC; k++) { llv[k] = acc[k] + m2lp[k]; mx = fmaxf(mx, llv[k]); }
    float s = 0.f;
#pragma unroll
    for (int k = 0; k < KC; k++) s += expf(llv[k] - mx);
    const float log_pz = -0.5f * x2 + mx + logf(s) + LD * LOG_NORM;

    const float* lvr = &stats[bs * 128 + 64];
    const float* er = &eps[(bs * MC + m) * LD];
    float slv = 0.f, se2 = 0.f;
#pragma unroll
    for (int l4 = 0; l4 < 16; l4++) {
        const float4 lv = ((const float4*)lvr)[l4];
        slv += lv.x + lv.y + lv.z + lv.w;
        const float4 e = ((const float4*)er)[l4];
        se2 = fmaf(e.x, e.x, fmaf(e.y, e.y, fmaf(e.z, e.z, fmaf(e.w, e.w, se2))));
    }
    const float log_qz = -0.5f * (slv + se2) + LD * LOG_NORM;

    float v = log_qz - log_pz;
    v = warpReduceSum(v);
    if ((t & 63) == 0) redS[t >> 6] = v;
    __syncthreads();
    if (t == 0) atomicAdd(klAcc, redS[0] + redS[1] + redS[2] + redS[3]);
}

__global__ void finalize(const float* __restrict__ scal, float* __restrict__ out)
{
    if (threadIdx.x == 0) {
        out[0] = scal[0] * (1.f / (float)NROWS);
        out[1] = scal[1] * (1.f / (float)NROWS);
    }
}

// ---------------------------------------------------------------------------
extern "C" void kernel_launch(void* const* d_in, const int* in_sizes, int n_in,
                              void* d_out, int out_size, void* d_ws, size_t ws_size,
                              hipStream_t stream)
{
    const float* H   = (const float*)d_in[0];
    const float* eps = (const float*)d_in[1];
    const float* wq  = (const float*)d_in[2];
    const float* bq  = (const float*)d_in[3];
    const float* wk  = (const float*)d_in[4];
    const float* bk  = (const float*)d_in[5];
    const float* wv  = (const float*)d_in[6];
    const float* bv  = (const float*)d_in[7];
    const float* wo  = (const float*)d_in[8];
    const float* bo  = (const float*)d_in[9];
    const float* wz  = (const float*)d_in[10];
    const float* bz  = (const float*)d_in[11];
    const float* w1  = (const float*)d_in[12];
    const float* b1  = (const float*)d_in[13];
    const float* w2  = (const float*)d_in[14];
    const float* b2  = (const float*)d_in[15];
    const float* w3  = (const float*)d_in[16];
    const float* b3  = (const float*)d_in[17];
    const int* init_idx = (const int*)d_in[18];
    float* out = (float*)d_out;
    float* wsf = (float*)d_ws;

    // ---- workspace layout (float slots), total 18,984,960 floats = 75.9 MB
    const long o_scal  = 0;
    const long o_NkG   = 1024;
    const long o_musum = 2048;
    const long o_logpi = 23552;
    const long o_mu    = 24576;
    const long o_q     = 45056;      // 2097152 (also h2 at MAB2-oproj; z16 in decoder)
    const long o_k     = 2142208;    // 2097152 (d1 in decoder)
    const long o_vT    = 4239360;    // 2097152
    const long o_o     = 6336512;    // 2097152
    const long o_h1    = 8433664;    // 2097152 (h0 then h1; d2 in decoder)
    const long o_sc    = 10530816;   // 4194304 fp32 scores, att hi/lo in place
    const long o_wqkvT = 14725120;   // 786432  (w1T/w2T/w3T in decoder)
    const long o_woT   = 15511552;   // 262144
    const long o_wzT   = 15773696;   // 65536
    const long o_st    = 15839232;   // 524288
    const long o_zb    = 16363520;   // 2621440 -> end 18984960

    typedef __hip_bfloat16 bf;
    const long PL = (long)BS_TOT * DIM;  // 2097152 elements per plane
    bf* qh  = (bf*)(wsf + o_q);   bf* ql  = qh + PL;
    bf* kh  = (bf*)(wsf + o_k);   bf* kl_ = kh + PL;
    bf* vTh = (bf*)(wsf + o_vT);  bf* vTl = vTh + PL;
    bf* oh  = (bf*)(wsf + o_o);   bf* ol  = oh + PL;
    bf* h1h = (bf*)(wsf + o_h1);  bf* h1l = h1h + PL;   // h0 then h1
    bf* h2h = qh;                 bf* h2l = ql;         // alias q (dead then)
    float* sc = wsf + o_sc;
    bf* atth = (bf*)sc;           bf* attl_unused = nullptr; (void)attl_unused;
    bf* wqkvTh = (bf*)(wsf + o_wqkvT); bf* wqkvTl = wqkvTh + 1536L * 512;
    bf* woTh = (bf*)(wsf + o_woT);     bf* woTl = woTh + 512L * 512;
    bf* wzTh = (bf*)(wsf + o_wzT);     bf* wzTl = wzTh + 128L * 512;
    float* st = wsf + o_st;
    float* zb = wsf + o_zb;
    float* scal = wsf + o_scal;
    // decoder overlays
    bf* z16 = qh;                                   // q region
    bf* w1T = wqkvTh;                               // 1024x64
    bf* w2T = w1T + 1024L * 64;                     // 1024x1024
    bf* w3T = w2T + 1024L * 1024;                   // 512x1024
    bf* d1  = (bf*)(wsf + o_k);                     // 10240x1024 (k..o regions)
    bf* d2  = (bf*)(wsf + o_h1);                    // 10240x1024 (h1+sc regions)

    hipMemsetAsync(scal, 0, 64, stream);

    const dim3 blk(256);
    const long SD = (long)SEQ * DIM;  // 131072
    const float inv_sqrt_d = 0.044194173824159216f;

    // ---- input H -> split planes (into h1 region, serves as h0) ----
    conv_split_flat<<<(int)((PL + 255) / 256), blk, 0, stream>>>(H, h1h, h1l, (int)PL);

    // ---- 2x MAB on split-bf16 MFMA ----
    for (int i = 0; i < 2; i++) {
        const long woff = (long)i * DIM * DIM, boff = (long)i * DIM;
        // weights -> transposed split (wqkvT: [wq|wk|wv] rows 0..1535)
        conv_split_T<<<1024, blk, 0, stream>>>(wq + woff, wqkvTh, wqkvTl, 512, 512);
        conv_split_T<<<1024, blk, 0, stream>>>(wk + woff, wqkvTh + 512L * 512, wqkvTl + 512L * 512, 512, 512);
        conv_split_T<<<1024, blk, 0, stream>>>(wv + woff, wqkvTh + 1024L * 512, wqkvTl + 1024L * 512, 512, 512);
        conv_split_T<<<1024, blk, 0, stream>>>(wo + woff, woTh, woTl, 512, 512);

        // QKV fused: [q|k|vT] = h @ [wq|wk|wv] + b
        gemm3<0><<<dim3(12, 32, 1), blk, 0, stream>>>(
            h1h, h1l, wqkvTh, wqkvTl, 512, 512, 512, 0, 0, 0, 0,
            bq + boff, bk + boff, bv + boff, 1.f, nullptr,
            qh, ql, kh, kl_, vTh, vTl, nullptr, nullptr);
        // scores = q @ k^T / sqrt(D)  (per b,h)
        gemm3<1><<<dim3(2, 2, 64), blk, 0, stream>>>(
            qh, ql, kh, kl_, 128, 512, 512, SD, 128, SD, 128,
            nullptr, nullptr, nullptr, inv_sqrt_d, sc,
            nullptr, nullptr, nullptr, nullptr, nullptr, nullptr, nullptr, nullptr);
        softmax_att<<<4096, blk, 0, stream>>>(sc);
        // o = q + att @ v  (att in-place hi/lo over sc; vT pre-transposed)
        gemm3<2><<<dim3(1, 2, 64), blk, 0, stream>>>(
            atth, atth + 256, vTh, vTl, 256, 512, 256,
            524288, 131072, 131072, 32768,
            nullptr, nullptr, nullptr, 1.f, nullptr,
            oh, ol, nullptr, nullptr, nullptr, nullptr, qh, ql);
        // h = o + relu(o @ wo + bo)
        bf* houth = (i == 0) ? h1h : h2h;
        bf* houtl = (i == 0) ? h1l : h2l;
        gemm3<3><<<dim3(4, 32, 1), blk, 0, stream>>>(
            oh, ol, woTh, woTl, 512, 512, 512, 0, 0, 0, 0,
            bo + boff, nullptr, nullptr, 1.f, nullptr,
            houth, houtl, nullptr, nullptr, nullptr, nullptr, oh, ol);
    }

    // ---- stats = h2 @ wz + bz (fp32 out) ----
    conv_split_T<<<256, blk, 0, stream>>>(wz, wzTh, wzTl, 512, 128);
    gemm3<4><<<dim3(1, 32, 1), blk, 0, stream>>>(
        h2h, h2l, wzTh, wzTl, 512, 512, 512, 0, 0, 0, 0,
        bz, nullptr, nullptr, 1.f, st,
        nullptr, nullptr, nullptr, nullptr, nullptr, nullptr, nullptr, nullptr);

    // ---- z (fp32 exact + bf16 copy; z16 overlays dead q region) ----
    zgen<<<2560, blk, 0, stream>>>(st, eps, zb, z16);

    // ---- decoder weights (plain bf16) ----
    convert_wT<<<(64 * 1024 + 255) / 256, blk, 0, stream>>>(w1, w1T, 64, 1024);
    convert_wT<<<(1024 * 1024 + 255) / 256, blk, 0, stream>>>(w2, w2T, 1024, 1024);
    convert_wT<<<(1024 * 512 + 255) / 256, blk, 0, stream>>>(w3, w3T, 1024, 512);

    // ---- decoder MLP + fused rec_loss, 4 chunks of 10240 rows ----
    for (int c = 0; c < 4; c++) {
        const long rows0 = (long)c * 10240;
        gemm_mfma<false><<<dim3(8, 80), blk, 0, stream>>>(
            z16 + rows0 * LD, w1T, d1, b1, nullptr, nullptr, 64, 1024, 0);
        gemm_mfma<false><<<dim3(8, 80), blk, 0, stream>>>(
            d1, w2T, d2, b2, nullptr, nullptr, 1024, 1024, 0);
        gemm_mfma<true><<<dim3(4, 80), blk, 0, stream>>>(
            d2, w3T, nullptr, b3, H, scal + 0, 1024, 512, (int)rows0);
    }

    // ---- EM (fp32, exact) ----
    em_init<<<16, blk, 0, stream>>>(zb, init_idx, wsf + o_mu, wsf + o_logpi,
                                    wsf + o_musum, wsf + o_NkG);
    for (int it = 0; it < 5; it++) {
        em_step<<<dim3(10, 16), blk, 0, stream>>>(zb, wsf + o_mu, wsf + o_logpi,
                                                  wsf + o_musum, wsf + o_NkG);
        em_update<<<16, 64, 0, stream>>>(wsf + o_mu, wsf + o_logpi,
                                         wsf + o_musum, wsf + o_NkG);
    }

    // ---- KL (fp32, exact) ----
    kl_kernel<<<dim3(10, 16), blk, 0, stream>>>(zb, st, eps, wsf + o_mu,
                                                wsf + o_logpi, scal + 1);

    finalize<<<1, 64, 0, stream>>>(scal, out);
}

// Round 4
// 866.412 us; speedup vs baseline: 4.7036x; 1.0867x over previous
//
#include <hip/hip_runtime.h>
#include <hip/hip_bf16.h>
#include <math.h>

// ---------------------------------------------------------------------------
// GMVAE fused pipeline. Round 4: gemm3 single-pass 4-plane staging (3 MFMA
// groups per barrier), fused scores+softmax kernel, batched weight converts.
// B=16 S=256 D=512 H_heads=4 dh=128 L=64 K=20 MC=10 EM_ITERS=5
// ---------------------------------------------------------------------------

#define BATCH 16
#define SEQ 256
#define DIM 512
#define NH 4
#define DH 128
#define LD 64
#define KC 20
#define MC 10
#define NPTS 2560
#define BS_TOT 4096
#define NROWS 40960
#define LOG_NORM (-0.9189385332046727f)

typedef __attribute__((ext_vector_type(8))) short bf16x8;
typedef __attribute__((ext_vector_type(4))) float f32x4;

__device__ inline float warpReduceSum(float v) {
    for (int o = 32; o > 0; o >>= 1) v += __shfl_down(v, o);
    return v;
}
__device__ inline float warpReduceMax(float v) {
    for (int o = 32; o > 0; o >>= 1) v = fmaxf(v, __shfl_down(v, o));
    return v;
}

__device__ inline void async_copy16(const __hip_bfloat16* g, __hip_bfloat16* l) {
    __builtin_amdgcn_global_load_lds(
        (const __attribute__((address_space(1))) unsigned int*)g,
        (__attribute__((address_space(3))) unsigned int*)l, 16, 0, 0);
}

__device__ inline void split_store(float x, __hip_bfloat16* ph, __hip_bfloat16* pl, long idx) {
    const __hip_bfloat16 h = __float2bfloat16(x);
    ph[idx] = h;
    pl[idx] = __float2bfloat16(x - __bfloat162float(h));
}

// ---------------------------------------------------------------------------
// Split-bf16 MFMA GEMM, single-pass staging: per k-tile stage Ah/Al/Bh/Bl
// once, run 3 MFMA groups (AhBh + AhBl + AlBh) per barrier. fp32-equivalent.
// 128x128 tile, BK=32, 4 waves x (4x4) 16x16x32 MFMAs per group.
// MODE: 0=QKV(fused q/k/vT out) 2=PV(+q resid, o out)
//       3=OPROJ(bias,relu,+o resid, h out) 4=STATS(fp32 out +bias)
// ---------------------------------------------------------------------------
template<int MODE>
__global__ __launch_bounds__(256, 2)
void gemm3(const __hip_bfloat16* __restrict__ Ah, const __hip_bfloat16* __restrict__ Al,
           const __hip_bfloat16* __restrict__ Bh, const __hip_bfloat16* __restrict__ Bl,
           int K, int lda, int ldb,
           long aZb, long aZh, long bZb, long bZh,
           const float* __restrict__ b0, const float* __restrict__ b1v,
           const float* __restrict__ b2v,
           float* __restrict__ outF,
           __hip_bfloat16* __restrict__ P1h, __hip_bfloat16* __restrict__ P1l,
           __hip_bfloat16* __restrict__ P2h, __hip_bfloat16* __restrict__ P2l,
           __hip_bfloat16* __restrict__ P3h, __hip_bfloat16* __restrict__ P3l,
           const __hip_bfloat16* __restrict__ Rh, const __hip_bfloat16* __restrict__ Rl)
{
    __shared__ __align__(16) __hip_bfloat16 Ash[128 * 32];
    __shared__ __align__(16) __hip_bfloat16 Asl[128 * 32];
    __shared__ __align__(16) __hip_bfloat16 Bsh[128 * 32];
    __shared__ __align__(16) __hip_bfloat16 Bsl[128 * 32];

    const int t = threadIdx.x;
    const int z = blockIdx.z;
    const int zb_ = z >> 2, zh_ = z & 3;
    const long aOff = (long)zb_ * aZb + (long)zh_ * aZh;
    const long bOff = (long)zb_ * bZb + (long)zh_ * bZh;

    const int m0 = blockIdx.y * 128, n0 = blockIdx.x * 128;
    const int w = t >> 6, lane = t & 63;
    const int wm = (w >> 1) * 64, wn = (w & 1) * 64;
    const int fm = lane & 15;
    const int fk = (lane >> 4) * 8;
    const int srow = t >> 2, scol = (t & 3) * 8;

    f32x4 acc[4][4];
#pragma unroll
    for (int i = 0; i < 4; i++)
#pragma unroll
        for (int j = 0; j < 4; j++) acc[i][j] = (f32x4){0.f, 0.f, 0.f, 0.f};

    __hip_bfloat16* lah = Ash + w * 512;
    __hip_bfloat16* lal = Asl + w * 512;
    __hip_bfloat16* lbh = Bsh + w * 512;
    __hip_bfloat16* lbl = Bsl + w * 512;

    const int nk = K >> 5;
    for (int kk = 0; kk < nk; kk++) {
        const long ao = aOff + (long)(m0 + srow) * lda + kk * 32 + scol;
        const long bo = bOff + (long)(n0 + srow) * ldb + kk * 32 + scol;
        async_copy16(Ah + ao, lah);
        async_copy16(Ah + ao + 64L * lda, lah + 2048);
        async_copy16(Al + ao, lal);
        async_copy16(Al + ao + 64L * lda, lal + 2048);
        async_copy16(Bh + bo, lbh);
        async_copy16(Bh + bo + 64L * ldb, lbh + 2048);
        async_copy16(Bl + bo, lbl);
        async_copy16(Bl + bo + 64L * ldb, lbl + 2048);
        __syncthreads();

        bf16x8 afh[4], afl[4], bfh[4], bfl[4];
#pragma unroll
        for (int mi = 0; mi < 4; mi++) {
            afh[mi] = *(const bf16x8*)&Ash[(wm + mi * 16 + fm) * 32 + fk];
            afl[mi] = *(const bf16x8*)&Asl[(wm + mi * 16 + fm) * 32 + fk];
        }
#pragma unroll
        for (int ni = 0; ni < 4; ni++) {
            bfh[ni] = *(const bf16x8*)&Bsh[(wn + ni * 16 + fm) * 32 + fk];
            bfl[ni] = *(const bf16x8*)&Bsl[(wn + ni * 16 + fm) * 32 + fk];
        }
#pragma unroll
        for (int mi = 0; mi < 4; mi++)
#pragma unroll
            for (int ni = 0; ni < 4; ni++) {
                acc[mi][ni] = __builtin_amdgcn_mfma_f32_16x16x32_bf16(
                    afh[mi], bfh[ni], acc[mi][ni], 0, 0, 0);
                acc[mi][ni] = __builtin_amdgcn_mfma_f32_16x16x32_bf16(
                    afh[mi], bfl[ni], acc[mi][ni], 0, 0, 0);
                acc[mi][ni] = __builtin_amdgcn_mfma_f32_16x16x32_bf16(
                    afl[mi], bfh[ni], acc[mi][ni], 0, 0, 0);
            }
        __syncthreads();
    }

    // epilogue: C/D layout col = lane&15 (within 16), row = (lane>>4)*4 + r
#pragma unroll
    for (int ni = 0; ni < 4; ni++) {
        const int col = n0 + wn + ni * 16 + fm;
#pragma unroll
        for (int mi = 0; mi < 4; mi++) {
#pragma unroll
            for (int r = 0; r < 4; r++) {
                const int row = m0 + wm + mi * 16 + (lane >> 4) * 4 + r;
                float x = acc[mi][ni][r];
                if (MODE == 0) {  // QKV fused: which 512-range of N=1536
                    const int which = n0 >> 9;
                    const int colq = col & 511;
                    if (which == 0) {
                        x += b0[colq];
                        split_store(x, P1h, P1l, (long)row * 512 + colq);
                    } else if (which == 1) {
                        x += b1v[colq];
                        split_store(x, P2h, P2l, (long)row * 512 + colq);
                    } else {  // v, written transposed per head: [b][h][d][s]
                        x += b2v[colq];
                        const int bb = row >> 8, s = row & 255;
                        const int hh = colq >> 7, dd = colq & 127;
                        const long idx = (((long)(bb * NH + hh) * DH + dd) * SEQ) + s;
                        split_store(x, P3h, P3l, idx);
                    }
                } else if (MODE == 2) {  // PV: o = q + att@v
                    const long idx = ((long)(zb_ * 256 + row)) * 512 + zh_ * 128 + col;
                    x += __bfloat162float(Rh[idx]) + __bfloat162float(Rl[idx]);
                    split_store(x, P1h, P1l, idx);
                } else if (MODE == 3) {  // OPROJ: h = o + relu(x + bo)
                    const long idx = (long)row * 512 + col;
                    x = fmaxf(x + b0[col], 0.f);
                    x += __bfloat162float(Rh[idx]) + __bfloat162float(Rl[idx]);
                    split_store(x, P1h, P1l, idx);
                } else {  // STATS fp32 out
                    outF[(long)row * 128 + col] = x + b0[col];
                }
            }
        }
    }
}

// ---------------------------------------------------------------------------
// Fused scores+softmax: per (b,h) and q-half, computes the full 128x256
// score tile (split-bf16, fp32-equivalent), does row softmax in-register
// (cross-wave via LDS), writes att as hi/lo bf16 ([z][256 rows][512]).
// grid (2, 64) x 256 threads.
// ---------------------------------------------------------------------------
__global__ __launch_bounds__(256)
void attn_scores(const __hip_bfloat16* __restrict__ qh, const __hip_bfloat16* __restrict__ ql,
                 const __hip_bfloat16* __restrict__ kh, const __hip_bfloat16* __restrict__ kl,
                 __hip_bfloat16* __restrict__ att)
{
    __shared__ __align__(16) __hip_bfloat16 Ash[128 * 32];
    __shared__ __align__(16) __hip_bfloat16 Asl[128 * 32];
    __shared__ __align__(16) __hip_bfloat16 Bsh[256 * 32];
    __shared__ __align__(16) __hip_bfloat16 Bsl[256 * 32];
    __shared__ float red[128][2];
    __shared__ float red2[128][2];

    const int t = threadIdx.x;
    const int z = blockIdx.y;
    const int m0 = blockIdx.x * 128;
    const long hOff = (long)(z >> 2) * 131072 + (long)(z & 3) * 128;  // q/k head base

    const int w = t >> 6, lane = t & 63;
    const int wm = (w >> 1) * 64, wn = (w & 1) * 128;
    const int fm = lane & 15;
    const int fk = (lane >> 4) * 8;
    const int srow = t >> 2, scol = (t & 3) * 8;

    f32x4 acc[4][8];
#pragma unroll
    for (int i = 0; i < 4; i++)
#pragma unroll
        for (int j = 0; j < 8; j++) acc[i][j] = (f32x4){0.f, 0.f, 0.f, 0.f};

    __hip_bfloat16* lah = Ash + w * 512;
    __hip_bfloat16* lal = Asl + w * 512;
    __hip_bfloat16* lbh = Bsh + w * 512;
    __hip_bfloat16* lbl = Bsl + w * 512;

    for (int kk = 0; kk < 4; kk++) {  // K = 128
        const long ao = hOff + (long)(m0 + srow) * 512 + kk * 32 + scol;
        const long bo = hOff + (long)srow * 512 + kk * 32 + scol;
        async_copy16(qh + ao, lah);
        async_copy16(qh + ao + 64L * 512, lah + 2048);
        async_copy16(ql + ao, lal);
        async_copy16(ql + ao + 64L * 512, lal + 2048);
#pragma unroll
        for (int j = 0; j < 4; j++) {
            async_copy16(kh + bo + (long)j * 64 * 512, lbh + j * 2048);
            async_copy16(kl + bo + (long)j * 64 * 512, lbl + j * 2048);
        }
        __syncthreads();

        bf16x8 afh[4], afl[4];
#pragma unroll
        for (int mi = 0; mi < 4; mi++) {
            afh[mi] = *(const bf16x8*)&Ash[(wm + mi * 16 + fm) * 32 + fk];
            afl[mi] = *(const bf16x8*)&Asl[(wm + mi * 16 + fm) * 32 + fk];
        }
#pragma unroll
        for (int ni = 0; ni < 8; ni++) {
            const bf16x8 bh = *(const bf16x8*)&Bsh[(wn + ni * 16 + fm) * 32 + fk];
            const bf16x8 bl = *(const bf16x8*)&Bsl[(wn + ni * 16 + fm) * 32 + fk];
#pragma unroll
            for (int mi = 0; mi < 4; mi++) {
                acc[mi][ni] = __builtin_amdgcn_mfma_f32_16x16x32_bf16(
                    afh[mi], bh, acc[mi][ni], 0, 0, 0);
                acc[mi][ni] = __builtin_amdgcn_mfma_f32_16x16x32_bf16(
                    afh[mi], bl, acc[mi][ni], 0, 0, 0);
                acc[mi][ni] = __builtin_amdgcn_mfma_f32_16x16x32_bf16(
                    afl[mi], bh, acc[mi][ni], 0, 0, 0);
            }
        }
        __syncthreads();
    }

    const float alpha = 0.044194173824159216f;  // 1/sqrt(512)
    const int quad = lane >> 4;

    // scale, then row max partials
#pragma unroll
    for (int mi = 0; mi < 4; mi++)
#pragma unroll
        for (int ni = 0; ni < 8; ni++)
#pragma unroll
            for (int r = 0; r < 4; r++) acc[mi][ni][r] *= alpha;

#pragma unroll
    for (int mi = 0; mi < 4; mi++)
#pragma unroll
        for (int r = 0; r < 4; r++) {
            float m = -1e30f;
#pragma unroll
            for (int ni = 0; ni < 8; ni++) m = fmaxf(m, acc[mi][ni][r]);
            for (int o = 8; o > 0; o >>= 1) m = fmaxf(m, __shfl_xor(m, o));
            if (fm == 0) red[wm + mi * 16 + quad * 4 + r][w & 1] = m;
        }
    __syncthreads();

    // exp + row sum partials
#pragma unroll
    for (int mi = 0; mi < 4; mi++)
#pragma unroll
        for (int r = 0; r < 4; r++) {
            const int rl = wm + mi * 16 + quad * 4 + r;
            const float mx = fmaxf(red[rl][0], red[rl][1]);
            float s = 0.f;
#pragma unroll
            for (int ni = 0; ni < 8; ni++) {
                const float e = __expf(acc[mi][ni][r] - mx);
                acc[mi][ni][r] = e;
                s += e;
            }
            for (int o = 8; o > 0; o >>= 1) s += __shfl_xor(s, o);
            if (fm == 0) red2[rl][w & 1] = s;
        }
    __syncthreads();

    // normalize + split-store att
    __hip_bfloat16* base = att + (long)z * 131072;
#pragma unroll
    for (int mi = 0; mi < 4; mi++)
#pragma unroll
        for (int r = 0; r < 4; r++) {
            const int rl = wm + mi * 16 + quad * 4 + r;
            const float inv = 1.f / (red2[rl][0] + red2[rl][1]);
            const long rb = (long)(m0 + rl) * 512;
#pragma unroll
            for (int ni = 0; ni < 8; ni++) {
                const int col = wn + ni * 16 + fm;
                const float p = acc[mi][ni][r] * inv;
                const __hip_bfloat16 h = __float2bfloat16(p);
                base[rb + col] = h;
                base[rb + 256 + col] = __float2bfloat16(p - __bfloat162float(h));
            }
        }
}

// ---------------------------------------------------------------------------
// plain-bf16 MFMA GEMM for the decoder (round-2, verified).
// ---------------------------------------------------------------------------
template<bool SQLOSS>
__global__ __launch_bounds__(256, 2)
void gemm_mfma(const __hip_bfloat16* __restrict__ A,
               const __hip_bfloat16* __restrict__ BT,
               __hip_bfloat16* __restrict__ C,
               const float* __restrict__ bias,
               const float* __restrict__ Href,
               float* __restrict__ lossAcc,
               int K, int N, int rowOffset)
{
    __shared__ __align__(16) __hip_bfloat16 As[128 * 32];
    __shared__ __align__(16) __hip_bfloat16 Bs[128 * 32];
    __shared__ float redS[4];

    const int t = threadIdx.x;
    const int m0 = blockIdx.y * 128, n0 = blockIdx.x * 128;
    const int w = t >> 6, lane = t & 63;
    const int wm = (w >> 1) * 64, wn = (w & 1) * 64;
    const int fm = lane & 15;
    const int fk = (lane >> 4) * 8;
    const int srow = t >> 2, scol = (t & 3) * 8;

    f32x4 acc[4][4];
#pragma unroll
    for (int i = 0; i < 4; i++)
#pragma unroll
        for (int j = 0; j < 4; j++) acc[i][j] = (f32x4){0.f, 0.f, 0.f, 0.f};

    __hip_bfloat16* la = As + w * 512;
    __hip_bfloat16* lb = Bs + w * 512;

    const int nkt = K >> 5;
    for (int kt = 0; kt < nkt; kt++) {
        const __hip_bfloat16* ga = A + (long)(m0 + srow) * K + kt * 32 + scol;
        const __hip_bfloat16* gb = BT + (long)(n0 + srow) * K + kt * 32 + scol;
        async_copy16(ga, la);
        async_copy16(ga + 64L * K, la + 2048);
        async_copy16(gb, lb);
        async_copy16(gb + 64L * K, lb + 2048);
        __syncthreads();

        bf16x8 af[4], bfr[4];
#pragma unroll
        for (int mi = 0; mi < 4; mi++)
            af[mi] = *(const bf16x8*)&As[(wm + mi * 16 + fm) * 32 + fk];
#pragma unroll
        for (int ni = 0; ni < 4; ni++)
            bfr[ni] = *(const bf16x8*)&Bs[(wn + ni * 16 + fm) * 32 + fk];
#pragma unroll
        for (int mi = 0; mi < 4; mi++)
#pragma unroll
            for (int ni = 0; ni < 4; ni++)
                acc[mi][ni] = __builtin_amdgcn_mfma_f32_16x16x32_bf16(
                    af[mi], bfr[ni], acc[mi][ni], 0, 0, 0);
        __syncthreads();
    }

    float lsum = 0.f;
#pragma unroll
    for (int ni = 0; ni < 4; ni++) {
        const int col = n0 + wn + ni * 16 + fm;
        const float b = bias[col];
#pragma unroll
        for (int mi = 0; mi < 4; mi++) {
#pragma unroll
            for (int r = 0; r < 4; r++) {
                const int row = m0 + wm + mi * 16 + (lane >> 4) * 4 + r;
                float x = acc[mi][ni][r] + b;
                x = fmaxf(x, 0.f);
                if (SQLOSS) {
                    const float d = x - Href[(long)((rowOffset + row) / MC) * DIM + col];
                    lsum = fmaf(d, d, lsum);
                } else {
                    C[(long)row * N + col] = __float2bfloat16(x);
                }
            }
        }
    }
    if (SQLOSS) {
        lsum = warpReduceSum(lsum);
        if (lane == 0) redS[w] = lsum;
        __syncthreads();
        if (t == 0) atomicAdd(lossAcc, redS[0] + redS[1] + redS[2] + redS[3]);
    }
}

// ---------------------------------------------------------------------------
// batched converters
// ---------------------------------------------------------------------------
__global__ void conv_split_flat(const float* __restrict__ src,
                                __hip_bfloat16* __restrict__ dh,
                                __hip_bfloat16* __restrict__ dl, int n)
{
    const int i = blockIdx.x * 256 + threadIdx.x;
    if (i < n) {
        const float x = src[i];
        const __hip_bfloat16 h = __float2bfloat16(x);
        dh[i] = h;
        dl[i] = __float2bfloat16(x - __bfloat162float(h));
    }
}

// one launch: wq|wk|wv -> wqkvT split (rows 0..1535), wo -> woT split.
// grid 4096 x 256 (4 x 262144 elements)
__global__ void conv_mab_weights(const float* __restrict__ wq, const float* __restrict__ wk,
                                 const float* __restrict__ wv, const float* __restrict__ wo,
                                 __hip_bfloat16* __restrict__ qkvTh, __hip_bfloat16* __restrict__ qkvTl,
                                 __hip_bfloat16* __restrict__ woTh, __hip_bfloat16* __restrict__ woTl)
{
    const int idx = blockIdx.x * 256 + threadIdx.x;
    const int seg = idx >> 18, r = idx & 262143;
    const int k = r >> 9, n = r & 511;
    const float* src = (seg == 0) ? wq : (seg == 1) ? wk : (seg == 2) ? wv : wo;
    const float x = src[r];
    const __hip_bfloat16 h = __float2bfloat16(x);
    const __hip_bfloat16 l = __float2bfloat16(x - __bfloat162float(h));
    if (seg < 3) {
        const long o = (long)(seg * 512 + n) * 512 + k;
        qkvTh[o] = h; qkvTl[o] = l;
    } else {
        const long o = (long)n * 512 + k;
        woTh[o] = h; woTl[o] = l;
    }
}

// one launch: wz (split-T) + decoder w1/w2/w3 (plain-T). 6656 x 256.
__global__ void conv_misc_weights(const float* __restrict__ wz,
                                  __hip_bfloat16* __restrict__ wzTh, __hip_bfloat16* __restrict__ wzTl,
                                  const float* __restrict__ w1, __hip_bfloat16* __restrict__ w1T,
                                  const float* __restrict__ w2, __hip_bfloat16* __restrict__ w2T,
                                  const float* __restrict__ w3, __hip_bfloat16* __restrict__ w3T)
{
    const int idx = blockIdx.x * 256 + threadIdx.x;
    if (idx < 65536) {  // wz: 512x128 split-T
        const int k = idx >> 7, n = idx & 127;
        const float x = wz[idx];
        const __hip_bfloat16 h = __float2bfloat16(x);
        wzTh[(long)n * 512 + k] = h;
        wzTl[(long)n * 512 + k] = __float2bfloat16(x - __bfloat162float(h));
    } else if (idx < 131072) {  // w1: 64x1024 plain-T
        const int i = idx - 65536;
        const int k = i >> 10, n = i & 1023;
        w1T[(long)n * 64 + k] = __float2bfloat16(w1[i]);
    } else if (idx < 1179648) {  // w2: 1024x1024 plain-T
        const int i = idx - 131072;
        const int k = i >> 10, n = i & 1023;
        w2T[(long)n * 1024 + k] = __float2bfloat16(w2[i]);
    } else {  // w3: 1024x512 plain-T
        const int i = idx - 1179648;
        const int k = i >> 9, n = i & 511;
        w3T[(long)n * 1024 + k] = __float2bfloat16(w3[i]);
    }
}

// ---------------------------------------------------------------------------
__global__ __launch_bounds__(256)
void zgen(const float* __restrict__ stats, const float* __restrict__ eps,
          float* __restrict__ z, __hip_bfloat16* __restrict__ z16)
{
    const int idx = blockIdx.x * 256 + threadIdx.x;
    const int bs = idx / 160;
    const int r = idx % 160;
    const int l4 = r % 16;
    const float4 e = ((const float4*)eps)[idx];
    const float4 mn = ((const float4*)stats)[bs * 32 + l4];
    const float4 lv = ((const float4*)stats)[bs * 32 + 16 + l4];
    float4 zz;
    zz.x = fmaf(e.x, expf(0.5f * lv.x), mn.x);
    zz.y = fmaf(e.y, expf(0.5f * lv.y), mn.y);
    zz.z = fmaf(e.z, expf(0.5f * lv.z), mn.z);
    zz.w = fmaf(e.w, expf(0.5f * lv.w), mn.w);
    ((float4*)z)[idx] = zz;
    __hip_bfloat16* zp = z16 + (long)idx * 4;
    zp[0] = __float2bfloat16(zz.x);
    zp[1] = __float2bfloat16(zz.y);
    zp[2] = __float2bfloat16(zz.z);
    zp[3] = __float2bfloat16(zz.w);
}

// ---------------------------------------------------------------------------
__global__ void em_init(const float* __restrict__ z, const int* __restrict__ init_idx,
                        float* __restrict__ mu, float* __restrict__ logPi,
                        float* __restrict__ musum, float* __restrict__ NkG)
{
    const int b = blockIdx.x, t = threadIdx.x;
    for (int i = t; i < KC * LD; i += 256) {
        const int k = i >> 6, l = i & 63;
        const int idx = init_idx[b * KC + k];
        mu[b * KC * LD + i] = z[((long)b * NPTS + idx) * LD + l];
        musum[b * KC * LD + i] = 0.f;
    }
    if (t < KC) {
        logPi[b * KC + t] = -logf((float)KC);
        NkG[b * KC + t] = 0.f;
    }
}

__global__ __launch_bounds__(256)
void em_step(const float* __restrict__ z, const float* __restrict__ mu,
             const float* __restrict__ logPi,
             float* __restrict__ musum, float* __restrict__ NkG)
{
    __shared__ float muS[KC][65];
    __shared__ float m2lp[KC];
    __shared__ float postS[KC][256];
    __shared__ float NkS[KC];

    const int tile = blockIdx.x, b = blockIdx.y, t = threadIdx.x;

    for (int i = t; i < KC * LD; i += 256) muS[i >> 6][i & 63] = mu[b * KC * LD + i];
    __syncthreads();
    if (t < KC) {
        float s = 0.f;
        for (int l = 0; l < LD; l++) { const float m = muS[t][l]; s = fmaf(m, m, s); }
        m2lp[t] = -0.5f * s + logPi[b * KC + t];
    }
    __syncthreads();

    const long n = (long)tile * 256 + t;
    const float* zr = &z[((long)b * NPTS + n) * LD];
    float acc[KC];
#pragma unroll
    for (int k = 0; k < KC; k++) acc[k] = 0.f;
#pragma unroll
    for (int l4 = 0; l4 < 16; l4++) {
        const float4 zv = ((const float4*)zr)[l4];
#pragma unroll
        for (int k = 0; k < KC; k++) {
            acc[k] = fmaf(zv.x, muS[k][l4 * 4 + 0], acc[k]);
            acc[k] = fmaf(zv.y, muS[k][l4 * 4 + 1], acc[k]);
            acc[k] = fmaf(zv.z, muS[k][l4 * 4 + 2], acc[k]);
            acc[k] = fmaf(zv.w, muS[k][l4 * 4 + 3], acc[k]);
        }
    }
    float mx = -1e30f;
    float llv[KC];
#pragma unroll
    for (int k = 0; k < KC; k++) { llv[k] = acc[k] + m2lp[k]; mx = fmaxf(mx, llv[k]); }
    float s = 0.f;
#pragma unroll
    for (int k = 0; k < KC; k++) { llv[k] = expf(llv[k] - mx); s += llv[k]; }
    const float inv = 1.f / s;
#pragma unroll
    for (int k = 0; k < KC; k++) postS[k][t] = llv[k] * inv;
    __syncthreads();

    const int lane = t & 63, w = t >> 6;
#pragma unroll
    for (int kk = 0; kk < 5; kk++) {
        const int k = w * 5 + kk;
        float p = postS[k][lane] + postS[k][lane + 64] + postS[k][lane + 128] + postS[k][lane + 192];
        p = warpReduceSum(p);
        if (lane == 0) NkS[k] = p;
    }
    __syncthreads();

    const float* zb = &z[((long)b * NPTS + (long)tile * 256) * LD];
#pragma unroll
    for (int j = 0; j < 5; j++) {
        const int o = t + j * 256;
        const int k = o >> 6, l = o & 63;
        float sacc = 0.f;
        for (int n2 = 0; n2 < 256; n2++)
            sacc = fmaf(postS[k][n2], zb[n2 * LD + l], sacc);
        atomicAdd(&musum[b * KC * LD + o], sacc);
    }
    if (t < KC) atomicAdd(&NkG[b * KC + t], NkS[t]);
}

__global__ void em_update(float* __restrict__ mu, float* __restrict__ logPi,
                          float* __restrict__ musum, float* __restrict__ NkG)
{
    __shared__ float Nk[KC];
    const int b = blockIdx.x, t = threadIdx.x;
    if (t < KC) Nk[t] = NkG[b * KC + t];
    __syncthreads();
    float s = 0.f;
    for (int k = 0; k < KC; k++) s += Nk[k];
    if (t < KC) logPi[b * KC + t] = logf(Nk[t] / s);
    for (int i = t; i < KC * LD; i += 64) {
        const int k = i >> 6;
        mu[b * KC * LD + i] = musum[b * KC * LD + i] / Nk[k];
        musum[b * KC * LD + i] = 0.f;
    }
    __syncthreads();
    if (t < KC) NkG[b * KC + t] = 0.f;
}

__global__ __launch_bounds__(256)
void kl_kernel(const float* __restrict__ z, const float* __restrict__ stats,
               const float* __restrict__ eps,
               const float* __restrict__ mu, const float* __restrict__ logPi,
               float* __restrict__ klAcc)
{
    __shared__ float muS[KC][65];
    __shared__ float m2lp[KC];
    __shared__ float redS[4];

    const int tile = blockIdx.x, b = blockIdx.y, t = threadIdx.x;

    for (int i = t; i < KC * LD; i += 256) muS[i >> 6][i & 63] = mu[b * KC * LD + i];
    __syncthreads();
    if (t < KC) {
        float s = 0.f;
        for (int l = 0; l < LD; l++) { const float m = muS[t][l]; s = fmaf(m, m, s); }
        m2lp[t] = -0.5f * s + logPi[b * KC + t];
    }
    __syncthreads();

    const int n = tile * 256 + t;
    const int sidx = n / MC, m = n % MC;
    const long bs = (long)b * SEQ + sidx;
    const float* zr = &z[((long)b * NPTS + n) * LD];

    float acc[KC];
#pragma unroll
    for (int k = 0; k < KC; k++) acc[k] = 0.f;
    float x2 = 0.f;
#pragma unroll
    for (int l4 = 0; l4 < 16; l4++) {
        const float4 zv = ((const float4*)zr)[l4];
        x2 = fmaf(zv.x, zv.x, fmaf(zv.y, zv.y, fmaf(zv.z, zv.z, fmaf(zv.w, zv.w, x2))));
#pragma unroll
        for (int k = 0; k < KC; k++) {
            acc[k] = fmaf(zv.x, muS[k][l4 * 4 + 0], acc[k]);
            acc[k] = fmaf(zv.y, muS[k][l4 * 4 + 1], acc[k]);
            acc[k] = fmaf(zv.z, muS[k][l4 * 4 + 2], acc[k]);
            acc[k] = fmaf(zv.w, muS[k][l4 * 4 + 3], acc[k]);
        }
    }
    float mx = -1e30f;
    float llv[KC];
#pragma unroll
    for (int k = 0; k < KC; k++) { llv[k] = acc[k] + m2lp[k]; mx = fmaxf(mx, llv[k]); }
    float s = 0.f;
#pragma unroll
    for (int k = 0; k < KC; k++) s += expf(llv[k] - mx);
    const float log_pz = -0.5f * x2 + mx + logf(s) + LD * LOG_NORM;

    const float* lvr = &stats[bs * 128 + 64];
    const float* er = &eps[(bs * MC + m) * LD];
    float slv = 0.f, se2 = 0.f;
#pragma unroll
    for (int l4 = 0; l4 < 16; l4++) {
        const float4 lv = ((const float4*)lvr)[l4];
        slv += lv.x + lv.y + lv.z + lv.w;
        const float4 e = ((const float4*)er)[l4];
        se2 = fmaf(e.x, e.x, fmaf(e.y, e.y, fmaf(e.z, e.z, fmaf(e.w, e.w, se2))));
    }
    const float log_qz = -0.5f * (slv + se2) + LD * LOG_NORM;

    float v = log_qz - log_pz;
    v = warpReduceSum(v);
    if ((t & 63) == 0) redS[t >> 6] = v;
    __syncthreads();
    if (t == 0) atomicAdd(klAcc, redS[0] + redS[1] + redS[2] + redS[3]);
}

__global__ void finalize(const float* __restrict__ scal, float* __restrict__ out)
{
    if (threadIdx.x == 0) {
        out[0] = scal[0] * (1.f / (float)NROWS);
        out[1] = scal[1] * (1.f / (float)NROWS);
    }
}

// ---------------------------------------------------------------------------
extern "C" void kernel_launch(void* const* d_in, const int* in_sizes, int n_in,
                              void* d_out, int out_size, void* d_ws, size_t ws_size,
                              hipStream_t stream)
{
    const float* H   = (const float*)d_in[0];
    const float* eps = (const float*)d_in[1];
    const float* wq  = (const float*)d_in[2];
    const float* bq  = (const float*)d_in[3];
    const float* wk  = (const float*)d_in[4];
    const float* bk  = (const float*)d_in[5];
    const float* wv  = (const float*)d_in[6];
    const float* bv  = (const float*)d_in[7];
    const float* wo  = (const float*)d_in[8];
    const float* bo  = (const float*)d_in[9];
    const float* wz  = (const float*)d_in[10];
    const float* bz  = (const float*)d_in[11];
    const float* w1  = (const float*)d_in[12];
    const float* b1  = (const float*)d_in[13];
    const float* w2  = (const float*)d_in[14];
    const float* b2  = (const float*)d_in[15];
    const float* w3  = (const float*)d_in[16];
    const float* b3  = (const float*)d_in[17];
    const int* init_idx = (const int*)d_in[18];
    float* out = (float*)d_out;
    float* wsf = (float*)d_ws;

    // ---- workspace layout (float slots), total 18,984,960 floats = 75.9 MB
    const long o_scal  = 0;
    const long o_NkG   = 1024;
    const long o_musum = 2048;
    const long o_logpi = 23552;
    const long o_mu    = 24576;
    const long o_q     = 45056;      // 2097152 (h2 at MAB2-oproj; z16 in decoder)
    const long o_k     = 2142208;    // 2097152 (d1 in decoder)
    const long o_vT    = 4239360;    // 2097152
    const long o_o     = 6336512;    // 2097152
    const long o_h1    = 8433664;    // 2097152 (h0 then h1; d2 in decoder)
    const long o_sc    = 10530816;   // 4194304: att hi/lo bf16 [64][256][512]
    const long o_wqkvT = 14725120;   // 786432  (w1T/w2T/w3T in decoder)
    const long o_woT   = 15511552;   // 262144
    const long o_wzT   = 15773696;   // 65536
    const long o_st    = 15839232;   // 524288
    const long o_zb    = 16363520;   // 2621440 -> end 18984960

    typedef __hip_bfloat16 bf;
    const long PL = (long)BS_TOT * DIM;  // 2097152 elements per plane
    bf* qh  = (bf*)(wsf + o_q);   bf* ql  = qh + PL;
    bf* kh  = (bf*)(wsf + o_k);   bf* kl_ = kh + PL;
    bf* vTh = (bf*)(wsf + o_vT);  bf* vTl = vTh + PL;
    bf* oh  = (bf*)(wsf + o_o);   bf* ol  = oh + PL;
    bf* h1h = (bf*)(wsf + o_h1);  bf* h1l = h1h + PL;   // h0 then h1
    bf* h2h = qh;                 bf* h2l = ql;         // alias q (dead then)
    bf* att = (bf*)(wsf + o_sc);
    bf* wqkvTh = (bf*)(wsf + o_wqkvT); bf* wqkvTl = wqkvTh + 1536L * 512;
    bf* woTh = (bf*)(wsf + o_woT);     bf* woTl = woTh + 512L * 512;
    bf* wzTh = (bf*)(wsf + o_wzT);     bf* wzTl = wzTh + 128L * 512;
    float* st = wsf + o_st;
    float* zb = wsf + o_zb;
    float* scal = wsf + o_scal;
    // decoder overlays
    bf* z16 = qh;                                   // q region
    bf* w1T = wqkvTh;                               // 1024x64
    bf* w2T = w1T + 1024L * 64;                     // 1024x1024
    bf* w3T = w2T + 1024L * 1024;                   // 512x1024
    bf* d1  = (bf*)(wsf + o_k);                     // 10240x1024 (k..o regions)
    bf* d2  = (bf*)(wsf + o_h1);                    // 10240x1024 (h1+sc regions)

    hipMemsetAsync(scal, 0, 64, stream);

    const dim3 blk(256);
    const long SD = (long)SEQ * DIM;  // 131072

    // ---- input H -> split planes (h1 region serves as h0) ----
    conv_split_flat<<<(int)((PL + 255) / 256), blk, 0, stream>>>(H, h1h, h1l, (int)PL);

    // ---- 2x MAB on split-bf16 MFMA ----
    for (int i = 0; i < 2; i++) {
        const long woff = (long)i * DIM * DIM, boff = (long)i * DIM;
        conv_mab_weights<<<4096, blk, 0, stream>>>(
            wq + woff, wk + woff, wv + woff, wo + woff,
            wqkvTh, wqkvTl, woTh, woTl);

        // QKV fused: [q|k|vT] = h @ [wq|wk|wv] + b
        gemm3<0><<<dim3(12, 32, 1), blk, 0, stream>>>(
            h1h, h1l, wqkvTh, wqkvTl, 512, 512, 512, 0, 0, 0, 0,
            bq + boff, bk + boff, bv + boff, nullptr,
            qh, ql, kh, kl_, vTh, vTl, nullptr, nullptr);
        // att = softmax(q @ k^T / sqrt(D)) as hi/lo bf16
        attn_scores<<<dim3(2, 64), blk, 0, stream>>>(qh, ql, kh, kl_, att);
        // o = q + att @ v  (vT pre-transposed per head)
        gemm3<2><<<dim3(1, 2, 64), blk, 0, stream>>>(
            att, att + 256, vTh, vTl, 256, 512, 256,
            524288, 131072, 131072, 32768,
            nullptr, nullptr, nullptr, nullptr,
            oh, ol, nullptr, nullptr, nullptr, nullptr, qh, ql);
        // h = o + relu(o @ wo + bo)
        bf* houth = (i == 0) ? h1h : h2h;
        bf* houtl = (i == 0) ? h1l : h2l;
        gemm3<3><<<dim3(4, 32, 1), blk, 0, stream>>>(
            oh, ol, woTh, woTl, 512, 512, 512, 0, 0, 0, 0,
            bo + boff, nullptr, nullptr, nullptr,
            houth, houtl, nullptr, nullptr, nullptr, nullptr, oh, ol);
    }

    // ---- misc weights (wz split + decoder plain) in one launch ----
    conv_misc_weights<<<6656, blk, 0, stream>>>(wz, wzTh, wzTl, w1, w1T, w2, w2T, w3, w3T);

    // ---- stats = h2 @ wz + bz (fp32 out) ----
    gemm3<4><<<dim3(1, 32, 1), blk, 0, stream>>>(
        h2h, h2l, wzTh, wzTl, 512, 512, 512, 0, 0, 0, 0,
        bz, nullptr, nullptr, st,
        nullptr, nullptr, nullptr, nullptr, nullptr, nullptr, nullptr, nullptr);

    // ---- z (fp32 exact + bf16 copy; z16 overlays dead q region) ----
    zgen<<<2560, blk, 0, stream>>>(st, eps, zb, z16);

    // ---- decoder MLP + fused rec_loss, 4 chunks of 10240 rows ----
    for (int c = 0; c < 4; c++) {
        const long rows0 = (long)c * 10240;
        gemm_mfma<false><<<dim3(8, 80), blk, 0, stream>>>(
            z16 + rows0 * LD, w1T, d1, b1, nullptr, nullptr, 64, 1024, 0);
        gemm_mfma<false><<<dim3(8, 80), blk, 0, stream>>>(
            d1, w2T, d2, b2, nullptr, nullptr, 1024, 1024, 0);
        gemm_mfma<true><<<dim3(4, 80), blk, 0, stream>>>(
            d2, w3T, nullptr, b3, H, scal + 0, 1024, 512, (int)rows0);
    }

    // ---- EM (fp32, exact) ----
    em_init<<<16, blk, 0, stream>>>(zb, init_idx, wsf + o_mu, wsf + o_logpi,
                                    wsf + o_musum, wsf + o_NkG);
    for (int it = 0; it < 5; it++) {
        em_step<<<dim3(10, 16), blk, 0, stream>>>(zb, wsf + o_mu, wsf + o_logpi,
                                                  wsf + o_musum, wsf + o_NkG);
        em_update<<<16, 64, 0, stream>>>(wsf + o_mu, wsf + o_logpi,
                                         wsf + o_musum, wsf + o_NkG);
    }

    // ---- KL (fp32, exact) ----
    kl_kernel<<<dim3(10, 16), blk, 0, stream>>>(zb, st, eps, wsf + o_mu,
                                                wsf + o_logpi, scal + 1);

    finalize<<<1, 64, 0, stream>>>(scal, out);
}

// Round 5
// 819.603 us; speedup vs baseline: 4.9722x; 1.0571x over previous
//
#include <hip/hip_runtime.h>
#include <hip/hip_bf16.h>
#include <math.h>

// ---------------------------------------------------------------------------
// GMVAE fused pipeline. Round 5: double-buffered K-loops in all GEMMs,
// fused flash-style attention (scores+softmax+PV+residual in one kernel).
// Split-bf16 (hi/lo) = fp32-equivalent accuracy on the MAB path.
// B=16 S=256 D=512 H_heads=4 dh=128 L=64 K=20 MC=10 EM_ITERS=5
// ---------------------------------------------------------------------------

#define BATCH 16
#define SEQ 256
#define DIM 512
#define NH 4
#define DH 128
#define LD 64
#define KC 20
#define MC 10
#define NPTS 2560
#define BS_TOT 4096
#define NROWS 40960
#define LOG_NORM (-0.9189385332046727f)

typedef __attribute__((ext_vector_type(8))) short bf16x8;
typedef __attribute__((ext_vector_type(4))) float f32x4;
typedef __hip_bfloat16 bf;

__device__ inline float warpReduceSum(float v) {
    for (int o = 32; o > 0; o >>= 1) v += __shfl_down(v, o);
    return v;
}
__device__ inline float warpReduceMax(float v) {
    for (int o = 32; o > 0; o >>= 1) v = fmaxf(v, __shfl_down(v, o));
    return v;
}

__device__ inline void async_copy16(const bf* g, bf* l) {
    __builtin_amdgcn_global_load_lds(
        (const __attribute__((address_space(1))) unsigned int*)g,
        (__attribute__((address_space(3))) unsigned int*)l, 16, 0, 0);
}

__device__ inline void split_store(float x, bf* ph, bf* pl, long idx) {
    const bf h = __float2bfloat16(x);
    ph[idx] = h;
    pl[idx] = __float2bfloat16(x - __bfloat162float(h));
}

// ---------------------------------------------------------------------------
// Split-bf16 MFMA GEMM, double-buffered: per k-tile stage Ah/Al/Bh/Bl for
// tile k+1 while computing tile k (3 MFMA groups AhBh+AhBl+AlBh).
// 128x128 tile, BK=32, 4 waves x (4x4) 16x16x32 MFMAs per group.
// MODE: 0=QKV(fused q/k/vT out) 3=OPROJ(bias,relu,+resid) 4=STATS(fp32+bias)
// ---------------------------------------------------------------------------
template<int MODE>
__global__ __launch_bounds__(256, 2)
void gemm3(const bf* __restrict__ Ah, const bf* __restrict__ Al,
           const bf* __restrict__ Bh, const bf* __restrict__ Bl,
           int K, int lda, int ldb,
           const float* __restrict__ b0, const float* __restrict__ b1v,
           const float* __restrict__ b2v,
           float* __restrict__ outF,
           bf* __restrict__ P1h, bf* __restrict__ P1l,
           bf* __restrict__ P2h, bf* __restrict__ P2l,
           bf* __restrict__ P3h, bf* __restrict__ P3l,
           const bf* __restrict__ Rh, const bf* __restrict__ Rl)
{
    // [buf][plane 0=Ah 1=Al 2=Bh 3=Bl][128*32 elements] = 65536 B
    __shared__ __align__(16) bf smem[2][4][128 * 32];

    const int t = threadIdx.x;
    const int m0 = blockIdx.y * 128, n0 = blockIdx.x * 128;
    const int w = t >> 6, lane = t & 63;
    const int wm = (w >> 1) * 64, wn = (w & 1) * 64;
    const int fm = lane & 15;
    const int fk = (lane >> 4) * 8;
    const int srow = t >> 2, scol = (t & 3) * 8;

    f32x4 acc[4][4];
#pragma unroll
    for (int i = 0; i < 4; i++)
#pragma unroll
        for (int j = 0; j < 4; j++) acc[i][j] = (f32x4){0.f, 0.f, 0.f, 0.f};

    const int nk = K >> 5;

#define STAGE3(kk, bi) do { \
        const long ao = (long)(m0 + srow) * lda + (kk) * 32 + scol; \
        const long bo = (long)(n0 + srow) * ldb + (kk) * 32 + scol; \
        bf* d0 = &smem[bi][0][w * 512]; bf* d1 = &smem[bi][1][w * 512]; \
        bf* d2 = &smem[bi][2][w * 512]; bf* d3 = &smem[bi][3][w * 512]; \
        async_copy16(Ah + ao, d0); async_copy16(Ah + ao + 64L * lda, d0 + 2048); \
        async_copy16(Al + ao, d1); async_copy16(Al + ao + 64L * lda, d1 + 2048); \
        async_copy16(Bh + bo, d2); async_copy16(Bh + bo + 64L * ldb, d2 + 2048); \
        async_copy16(Bl + bo, d3); async_copy16(Bl + bo + 64L * ldb, d3 + 2048); \
    } while (0)

    STAGE3(0, 0);
    int buf = 0;
    for (int kk = 0; kk < nk; kk++) {
        __syncthreads();              // drains loads for smem[buf]
        if (kk + 1 < nk) STAGE3(kk + 1, buf ^ 1);

        bf16x8 afh[4], afl[4], bfh[4], bfl[4];
#pragma unroll
        for (int mi = 0; mi < 4; mi++) {
            afh[mi] = *(const bf16x8*)&smem[buf][0][(wm + mi * 16 + fm) * 32 + fk];
            afl[mi] = *(const bf16x8*)&smem[buf][1][(wm + mi * 16 + fm) * 32 + fk];
        }
#pragma unroll
        for (int ni = 0; ni < 4; ni++) {
            bfh[ni] = *(const bf16x8*)&smem[buf][2][(wn + ni * 16 + fm) * 32 + fk];
            bfl[ni] = *(const bf16x8*)&smem[buf][3][(wn + ni * 16 + fm) * 32 + fk];
        }
#pragma unroll
        for (int mi = 0; mi < 4; mi++)
#pragma unroll
            for (int ni = 0; ni < 4; ni++) {
                acc[mi][ni] = __builtin_amdgcn_mfma_f32_16x16x32_bf16(
                    afh[mi], bfh[ni], acc[mi][ni], 0, 0, 0);
                acc[mi][ni] = __builtin_amdgcn_mfma_f32_16x16x32_bf16(
                    afh[mi], bfl[ni], acc[mi][ni], 0, 0, 0);
                acc[mi][ni] = __builtin_amdgcn_mfma_f32_16x16x32_bf16(
                    afl[mi], bfh[ni], acc[mi][ni], 0, 0, 0);
            }
        buf ^= 1;
    }
#undef STAGE3

    // epilogue: C/D layout col = lane&15 (within 16), row = (lane>>4)*4 + r
#pragma unroll
    for (int ni = 0; ni < 4; ni++) {
        const int col = n0 + wn + ni * 16 + fm;
#pragma unroll
        for (int mi = 0; mi < 4; mi++) {
#pragma unroll
            for (int r = 0; r < 4; r++) {
                const int row = m0 + wm + mi * 16 + (lane >> 4) * 4 + r;
                float x = acc[mi][ni][r];
                if (MODE == 0) {  // QKV fused: which 512-range of N=1536
                    const int which = n0 >> 9;
                    const int colq = col & 511;
                    if (which == 0) {
                        x += b0[colq];
                        split_store(x, P1h, P1l, (long)row * 512 + colq);
                    } else if (which == 1) {
                        x += b1v[colq];
                        split_store(x, P2h, P2l, (long)row * 512 + colq);
                    } else {  // v, written transposed per head: [b][h][d][s]
                        x += b2v[colq];
                        const int bb = row >> 8, s = row & 255;
                        const int hh = colq >> 7, dd = colq & 127;
                        const long idx = (((long)(bb * NH + hh) * DH + dd) * SEQ) + s;
                        split_store(x, P3h, P3l, idx);
                    }
                } else if (MODE == 3) {  // OPROJ: h = o + relu(x + bo)
                    const long idx = (long)row * 512 + col;
                    x = fmaxf(x + b0[col], 0.f);
                    x += __bfloat162float(Rh[idx]) + __bfloat162float(Rl[idx]);
                    split_store(x, P1h, P1l, idx);
                } else {  // STATS fp32 out
                    outF[(long)row * 128 + col] = x + b0[col];
                }
            }
        }
    }
}

// ---------------------------------------------------------------------------
// Fused attention: per (b,h) and 64-q-row slab, computes S = q@k^T in regs
// (split-bf16, fp32-equivalent), softmax in-register (cross-wave LDS
// reduction), then o = q + P@V with P cycled through LDS in 32-wide k-chunks
// against staged vT tiles. grid (4, 64) x 256 threads.
// Wave layout phase1: wave w owns S[0:64][64w:64w+64]; phase2: o[0:64][32w:32w+32].
// ---------------------------------------------------------------------------
__global__ __launch_bounds__(256)
void attn_fused(const bf* __restrict__ qh, const bf* __restrict__ ql,
                const bf* __restrict__ kh, const bf* __restrict__ kl,
                const bf* __restrict__ vTh, const bf* __restrict__ vTl,
                bf* __restrict__ oh, bf* __restrict__ ol)
{
    __shared__ __align__(16) char smem[43008];
    // phase1: Qh[0,4096) Ql[4096,8192) Kh[8192,24576) Kl[24576,40960)
    // phase2: Psh[0,4096) Psl[4096,8192) Vsh[8192,16384) Vsl[16384,24576)
    // red at 40960 (64x4 f32), red2 at 41984 (64x4 f32)
    bf* Qsh = (bf*)smem;            bf* Qsl = (bf*)(smem + 4096);
    bf* Ksh = (bf*)(smem + 8192);   bf* Ksl = (bf*)(smem + 24576);
    bf* Psh = (bf*)smem;            bf* Psl = (bf*)(smem + 4096);
    bf* Vsh = (bf*)(smem + 8192);   bf* Vsl = (bf*)(smem + 16384);
    float (*red)[4]  = (float(*)[4])(smem + 40960);
    float (*red2)[4] = (float(*)[4])(smem + 41984);

    const int t = threadIdx.x;
    const int z = blockIdx.y;                 // b*4 + h
    const int m0 = blockIdx.x * 64;           // q-row slab
    const int bb = z >> 2, hh = z & 3;
    const long hOff = (long)bb * 131072 + (long)hh * 128;  // q/k head base
    const long vOff = (long)z * 32768;                     // vT [z][128][256]

    const int w = t >> 6, lane = t & 63;
    const int fm = lane & 15;
    const int quad = lane >> 4;
    const int fk = quad * 8;
    const int srow = t >> 2, scol = (t & 3) * 8;

    f32x4 acc[4][4];   // S fragment: rows mi*16.. , cols w*64 + ni*16..
#pragma unroll
    for (int i = 0; i < 4; i++)
#pragma unroll
        for (int j = 0; j < 4; j++) acc[i][j] = (f32x4){0.f, 0.f, 0.f, 0.f};

    // ---- phase 1: S = q @ k^T (K=128, 4 k-tiles, single-buffered) ----
    for (int kk = 0; kk < 4; kk++) {
        const long ao = hOff + (long)(m0 + srow) * 512 + kk * 32 + scol;
        const long bo = hOff + (long)srow * 512 + kk * 32 + scol;
        async_copy16(qh + ao, Qsh + w * 512);
        async_copy16(ql + ao, Qsl + w * 512);
#pragma unroll
        for (int j = 0; j < 4; j++) {
            async_copy16(kh + bo + (long)j * 64 * 512, Ksh + w * 512 + j * 2048);
            async_copy16(kl + bo + (long)j * 64 * 512, Ksl + w * 512 + j * 2048);
        }
        __syncthreads();

        bf16x8 afh[4], afl[4];
#pragma unroll
        for (int mi = 0; mi < 4; mi++) {
            afh[mi] = *(const bf16x8*)&Qsh[(mi * 16 + fm) * 32 + fk];
            afl[mi] = *(const bf16x8*)&Qsl[(mi * 16 + fm) * 32 + fk];
        }
#pragma unroll
        for (int ni = 0; ni < 4; ni++) {
            const bf16x8 bh = *(const bf16x8*)&Ksh[(w * 64 + ni * 16 + fm) * 32 + fk];
            const bf16x8 bl = *(const bf16x8*)&Ksl[(w * 64 + ni * 16 + fm) * 32 + fk];
#pragma unroll
            for (int mi = 0; mi < 4; mi++) {
                acc[mi][ni] = __builtin_amdgcn_mfma_f32_16x16x32_bf16(
                    afh[mi], bh, acc[mi][ni], 0, 0, 0);
                acc[mi][ni] = __builtin_amdgcn_mfma_f32_16x16x32_bf16(
                    afh[mi], bl, acc[mi][ni], 0, 0, 0);
                acc[mi][ni] = __builtin_amdgcn_mfma_f32_16x16x32_bf16(
                    afl[mi], bh, acc[mi][ni], 0, 0, 0);
            }
        }
        __syncthreads();
    }

    // ---- softmax over rows (raw max, exp(alpha*(x-max)), unnormalized) ----
    const float alpha = 0.044194173824159216f;  // 1/sqrt(512)
#pragma unroll
    for (int mi = 0; mi < 4; mi++)
#pragma unroll
        for (int r = 0; r < 4; r++) {
            float m = -1e30f;
#pragma unroll
            for (int ni = 0; ni < 4; ni++) m = fmaxf(m, acc[mi][ni][r]);
            for (int o = 8; o > 0; o >>= 1) m = fmaxf(m, __shfl_xor(m, o));
            if (fm == 0) red[mi * 16 + quad * 4 + r][w] = m;
        }
    __syncthreads();
    float invr[4][4];
#pragma unroll
    for (int mi = 0; mi < 4; mi++)
#pragma unroll
        for (int r = 0; r < 4; r++) {
            const int rl = mi * 16 + quad * 4 + r;
            const float mx = fmaxf(fmaxf(red[rl][0], red[rl][1]),
                                   fmaxf(red[rl][2], red[rl][3]));
            float s = 0.f;
#pragma unroll
            for (int ni = 0; ni < 4; ni++) {
                const float e = __expf((acc[mi][ni][r] - mx) * alpha);
                acc[mi][ni][r] = e;
                s += e;
            }
            for (int o = 8; o > 0; o >>= 1) s += __shfl_xor(s, o);
            if (fm == 0) red2[rl][w] = s;
        }
    __syncthreads();
#pragma unroll
    for (int mi = 0; mi < 4; mi++)
#pragma unroll
        for (int r = 0; r < 4; r++) {
            const int rl = mi * 16 + quad * 4 + r;
            invr[mi][r] = 1.f / (red2[rl][0] + red2[rl][1] + red2[rl][2] + red2[rl][3]);
        }

    // ---- phase 2: o = q + P @ V, P through LDS in 8 k-chunks of 32 ----
    f32x4 acc2[4][2];  // o fragment: rows mi*16.., cols w*32 + ni*16..
#pragma unroll
    for (int i = 0; i < 4; i++)
#pragma unroll
        for (int j = 0; j < 2; j++) acc2[i][j] = (f32x4){0.f, 0.f, 0.f, 0.f};

    for (int kc = 0; kc < 8; kc++) {
        // owner wave writes its normalized P chunk cols [32kc, 32kc+32)
        if (w == (kc >> 1)) {
            const int nib = (kc & 1) * 2;
#pragma unroll
            for (int mi = 0; mi < 4; mi++)
#pragma unroll
                for (int r = 0; r < 4; r++) {
                    const int row = mi * 16 + quad * 4 + r;
#pragma unroll
                    for (int j = 0; j < 2; j++) {
                        const float p = acc[mi][nib + j][r] * invr[mi][r];
                        const int cc = j * 16 + fm;
                        const bf h = __float2bfloat16(p);
                        Psh[row * 32 + cc] = h;
                        Psl[row * 32 + cc] = __float2bfloat16(p - __bfloat162float(h));
                    }
                }
        }
        // stage vT chunk: rows d 0..127, cols s [32kc, 32kc+32)
        const long vo = vOff + (long)srow * 256 + kc * 32 + scol;
        async_copy16(vTh + vo, Vsh + w * 512);
        async_copy16(vTh + vo + 64L * 256, Vsh + w * 512 + 2048);
        async_copy16(vTl + vo, Vsl + w * 512);
        async_copy16(vTl + vo + 64L * 256, Vsl + w * 512 + 2048);
        __syncthreads();

        bf16x8 pfh[4], pfl[4];
#pragma unroll
        for (int mi = 0; mi < 4; mi++) {
            pfh[mi] = *(const bf16x8*)&Psh[(mi * 16 + fm) * 32 + fk];
            pfl[mi] = *(const bf16x8*)&Psl[(mi * 16 + fm) * 32 + fk];
        }
#pragma unroll
        for (int ni = 0; ni < 2; ni++) {
            const bf16x8 vh = *(const bf16x8*)&Vsh[(w * 32 + ni * 16 + fm) * 32 + fk];
            const bf16x8 vl = *(const bf16x8*)&Vsl[(w * 32 + ni * 16 + fm) * 32 + fk];
#pragma unroll
            for (int mi = 0; mi < 4; mi++) {
                acc2[mi][ni] = __builtin_amdgcn_mfma_f32_16x16x32_bf16(
                    pfh[mi], vh, acc2[mi][ni], 0, 0, 0);
                acc2[mi][ni] = __builtin_amdgcn_mfma_f32_16x16x32_bf16(
                    pfh[mi], vl, acc2[mi][ni], 0, 0, 0);
                acc2[mi][ni] = __builtin_amdgcn_mfma_f32_16x16x32_bf16(
                    pfl[mi], vh, acc2[mi][ni], 0, 0, 0);
            }
        }
        __syncthreads();
    }

    // ---- epilogue: o = q + acc2 (split-store) ----
#pragma unroll
    for (int ni = 0; ni < 2; ni++) {
        const int col = hh * 128 + w * 32 + ni * 16 + fm;
#pragma unroll
        for (int mi = 0; mi < 4; mi++)
#pragma unroll
            for (int r = 0; r < 4; r++) {
                const int row = mi * 16 + quad * 4 + r;
                const long idx = (long)(bb * 256 + m0 + row) * 512 + col;
                const float x = acc2[mi][ni][r]
                    + __bfloat162float(qh[idx]) + __bfloat162float(ql[idx]);
                split_store(x, oh, ol, idx);
            }
    }
}

// ---------------------------------------------------------------------------
// plain-bf16 MFMA GEMM for the decoder, double-buffered.
// ---------------------------------------------------------------------------
template<bool SQLOSS>
__global__ __launch_bounds__(256, 2)
void gemm_mfma(const bf* __restrict__ A, const bf* __restrict__ BT,
               bf* __restrict__ C,
               const float* __restrict__ bias,
               const float* __restrict__ Href,
               float* __restrict__ lossAcc,
               int K, int N, int rowOffset)
{
    __shared__ __align__(16) bf smem[2][2][128 * 32];  // [buf][A/B]
    __shared__ float redS[4];

    const int t = threadIdx.x;
    const int m0 = blockIdx.y * 128, n0 = blockIdx.x * 128;
    const int w = t >> 6, lane = t & 63;
    const int wm = (w >> 1) * 64, wn = (w & 1) * 64;
    const int fm = lane & 15;
    const int fk = (lane >> 4) * 8;
    const int srow = t >> 2, scol = (t & 3) * 8;

    f32x4 acc[4][4];
#pragma unroll
    for (int i = 0; i < 4; i++)
#pragma unroll
        for (int j = 0; j < 4; j++) acc[i][j] = (f32x4){0.f, 0.f, 0.f, 0.f};

    const int nk = K >> 5;

#define STAGE1(kk, bi) do { \
        const bf* ga = A + (long)(m0 + srow) * K + (kk) * 32 + scol; \
        const bf* gb = BT + (long)(n0 + srow) * K + (kk) * 32 + scol; \
        bf* da = &smem[bi][0][w * 512]; bf* db = &smem[bi][1][w * 512]; \
        async_copy16(ga, da); async_copy16(ga + 64L * K, da + 2048); \
        async_copy16(gb, db); async_copy16(gb + 64L * K, db + 2048); \
    } while (0)

    STAGE1(0, 0);
    int buf = 0;
    for (int kt = 0; kt < nk; kt++) {
        __syncthreads();
        if (kt + 1 < nk) STAGE1(kt + 1, buf ^ 1);

        bf16x8 af[4], bfr[4];
#pragma unroll
        for (int mi = 0; mi < 4; mi++)
            af[mi] = *(const bf16x8*)&smem[buf][0][(wm + mi * 16 + fm) * 32 + fk];
#pragma unroll
        for (int ni = 0; ni < 4; ni++)
            bfr[ni] = *(const bf16x8*)&smem[buf][1][(wn + ni * 16 + fm) * 32 + fk];
#pragma unroll
        for (int mi = 0; mi < 4; mi++)
#pragma unroll
            for (int ni = 0; ni < 4; ni++)
                acc[mi][ni] = __builtin_amdgcn_mfma_f32_16x16x32_bf16(
                    af[mi], bfr[ni], acc[mi][ni], 0, 0, 0);
        buf ^= 1;
    }
#undef STAGE1

    float lsum = 0.f;
#pragma unroll
    for (int ni = 0; ni < 4; ni++) {
        const int col = n0 + wn + ni * 16 + fm;
        const float b = bias[col];
#pragma unroll
        for (int mi = 0; mi < 4; mi++) {
#pragma unroll
            for (int r = 0; r < 4; r++) {
                const int row = m0 + wm + mi * 16 + (lane >> 4) * 4 + r;
                float x = acc[mi][ni][r] + b;
                x = fmaxf(x, 0.f);
                if (SQLOSS) {
                    const float d = x - Href[(long)((rowOffset + row) / MC) * DIM + col];
                    lsum = fmaf(d, d, lsum);
                } else {
                    C[(long)row * N + col] = __float2bfloat16(x);
                }
            }
        }
    }
    if (SQLOSS) {
        lsum = warpReduceSum(lsum);
        if (lane == 0) redS[w] = lsum;
        __syncthreads();
        if (t == 0) atomicAdd(lossAcc, redS[0] + redS[1] + redS[2] + redS[3]);
    }
}

// ---------------------------------------------------------------------------
// batched converters
// ---------------------------------------------------------------------------
__global__ void conv_split_flat(const float* __restrict__ src,
                                bf* __restrict__ dh, bf* __restrict__ dl, int n)
{
    const int i = blockIdx.x * 256 + threadIdx.x;
    if (i < n) {
        const float x = src[i];
        const bf h = __float2bfloat16(x);
        dh[i] = h;
        dl[i] = __float2bfloat16(x - __bfloat162float(h));
    }
}

__global__ void conv_mab_weights(const float* __restrict__ wq, const float* __restrict__ wk,
                                 const float* __restrict__ wv, const float* __restrict__ wo,
                                 bf* __restrict__ qkvTh, bf* __restrict__ qkvTl,
                                 bf* __restrict__ woTh, bf* __restrict__ woTl)
{
    const int idx = blockIdx.x * 256 + threadIdx.x;
    const int seg = idx >> 18, r = idx & 262143;
    const int k = r >> 9, n = r & 511;
    const float* src = (seg == 0) ? wq : (seg == 1) ? wk : (seg == 2) ? wv : wo;
    const float x = src[r];
    const bf h = __float2bfloat16(x);
    const bf l = __float2bfloat16(x - __bfloat162float(h));
    if (seg < 3) {
        const long o = (long)(seg * 512 + n) * 512 + k;
        qkvTh[o] = h; qkvTl[o] = l;
    } else {
        const long o = (long)n * 512 + k;
        woTh[o] = h; woTl[o] = l;
    }
}

__global__ void conv_misc_weights(const float* __restrict__ wz,
                                  bf* __restrict__ wzTh, bf* __restrict__ wzTl,
                                  const float* __restrict__ w1, bf* __restrict__ w1T,
                                  const float* __restrict__ w2, bf* __restrict__ w2T,
                                  const float* __restrict__ w3, bf* __restrict__ w3T)
{
    const int idx = blockIdx.x * 256 + threadIdx.x;
    if (idx < 65536) {  // wz: 512x128 split-T
        const int k = idx >> 7, n = idx & 127;
        const float x = wz[idx];
        const bf h = __float2bfloat16(x);
        wzTh[(long)n * 512 + k] = h;
        wzTl[(long)n * 512 + k] = __float2bfloat16(x - __bfloat162float(h));
    } else if (idx < 131072) {  // w1: 64x1024 plain-T
        const int i = idx - 65536;
        const int k = i >> 10, n = i & 1023;
        w1T[(long)n * 64 + k] = __float2bfloat16(w1[i]);
    } else if (idx < 1179648) {  // w2: 1024x1024 plain-T
        const int i = idx - 131072;
        const int k = i >> 10, n = i & 1023;
        w2T[(long)n * 1024 + k] = __float2bfloat16(w2[i]);
    } else {  // w3: 1024x512 plain-T
        const int i = idx - 1179648;
        const int k = i >> 9, n = i & 511;
        w3T[(long)n * 1024 + k] = __float2bfloat16(w3[i]);
    }
}

// ---------------------------------------------------------------------------
__global__ __launch_bounds__(256)
void zgen(const float* __restrict__ stats, const float* __restrict__ eps,
          float* __restrict__ z, bf* __restrict__ z16)
{
    const int idx = blockIdx.x * 256 + threadIdx.x;
    const int bs = idx / 160;
    const int r = idx % 160;
    const int l4 = r % 16;
    const float4 e = ((const float4*)eps)[idx];
    const float4 mn = ((const float4*)stats)[bs * 32 + l4];
    const float4 lv = ((const float4*)stats)[bs * 32 + 16 + l4];
    float4 zz;
    zz.x = fmaf(e.x, expf(0.5f * lv.x), mn.x);
    zz.y = fmaf(e.y, expf(0.5f * lv.y), mn.y);
    zz.z = fmaf(e.z, expf(0.5f * lv.z), mn.z);
    zz.w = fmaf(e.w, expf(0.5f * lv.w), mn.w);
    ((float4*)z)[idx] = zz;
    bf* zp = z16 + (long)idx * 4;
    zp[0] = __float2bfloat16(zz.x);
    zp[1] = __float2bfloat16(zz.y);
    zp[2] = __float2bfloat16(zz.z);
    zp[3] = __float2bfloat16(zz.w);
}

// ---------------------------------------------------------------------------
__global__ void em_init(const float* __restrict__ z, const int* __restrict__ init_idx,
                        float* __restrict__ mu, float* __restrict__ logPi,
                        float* __restrict__ musum, float* __restrict__ NkG)
{
    const int b = blockIdx.x, t = threadIdx.x;
    for (int i = t; i < KC * LD; i += 256) {
        const int k = i >> 6, l = i & 63;
        const int idx = init_idx[b * KC + k];
        mu[b * KC * LD + i] = z[((long)b * NPTS + idx) * LD + l];
        musum[b * KC * LD + i] = 0.f;
    }
    if (t < KC) {
        logPi[b * KC + t] = -logf((float)KC);
        NkG[b * KC + t] = 0.f;
    }
}

__global__ __launch_bounds__(256)
void em_step(const float* __restrict__ z, const float* __restrict__ mu,
             const float* __restrict__ logPi,
             float* __restrict__ musum, float* __restrict__ NkG)
{
    __shared__ float muS[KC][65];
    __shared__ float m2lp[KC];
    __shared__ float postS[KC][256];
    __shared__ float NkS[KC];

    const int tile = blockIdx.x, b = blockIdx.y, t = threadIdx.x;

    for (int i = t; i < KC * LD; i += 256) muS[i >> 6][i & 63] = mu[b * KC * LD + i];
    __syncthreads();
    if (t < KC) {
        float s = 0.f;
        for (int l = 0; l < LD; l++) { const float m = muS[t][l]; s = fmaf(m, m, s); }
        m2lp[t] = -0.5f * s + logPi[b * KC + t];
    }
    __syncthreads();

    const long n = (long)tile * 256 + t;
    const float* zr = &z[((long)b * NPTS + n) * LD];
    float acc[KC];
#pragma unroll
    for (int k = 0; k < KC; k++) acc[k] = 0.f;
#pragma unroll
    for (int l4 = 0; l4 < 16; l4++) {
        const float4 zv = ((const float4*)zr)[l4];
#pragma unroll
        for (int k = 0; k < KC; k++) {
            acc[k] = fmaf(zv.x, muS[k][l4 * 4 + 0], acc[k]);
            acc[k] = fmaf(zv.y, muS[k][l4 * 4 + 1], acc[k]);
            acc[k] = fmaf(zv.z, muS[k][l4 * 4 + 2], acc[k]);
            acc[k] = fmaf(zv.w, muS[k][l4 * 4 + 3], acc[k]);
        }
    }
    float mx = -1e30f;
    float llv[KC];
#pragma unroll
    for (int k = 0; k < KC; k++) { llv[k] = acc[k] + m2lp[k]; mx = fmaxf(mx, llv[k]); }
    float s = 0.f;
#pragma unroll
    for (int k = 0; k < KC; k++) { llv[k] = expf(llv[k] - mx); s += llv[k]; }
    const float inv = 1.f / s;
#pragma unroll
    for (int k = 0; k < KC; k++) postS[k][t] = llv[k] * inv;
    __syncthreads();

    const int lane = t & 63, w = t >> 6;
#pragma unroll
    for (int kk = 0; kk < 5; kk++) {
        const int k = w * 5 + kk;
        float p = postS[k][lane] + postS[k][lane + 64] + postS[k][lane + 128] + postS[k][lane + 192];
        p = warpReduceSum(p);
        if (lane == 0) NkS[k] = p;
    }
    __syncthreads();

    const float* zb = &z[((long)b * NPTS + (long)tile * 256) * LD];
#pragma unroll
    for (int j = 0; j < 5; j++) {
        const int o = t + j * 256;
        const int k = o >> 6, l = o & 63;
        float sacc = 0.f;
        for (int n2 = 0; n2 < 256; n2++)
            sacc = fmaf(postS[k][n2], zb[n2 * LD + l], sacc);
        atomicAdd(&musum[b * KC * LD + o], sacc);
    }
    if (t < KC) atomicAdd(&NkG[b * KC + t], NkS[t]);
}

__global__ void em_update(float* __restrict__ mu, float* __restrict__ logPi,
                          float* __restrict__ musum, float* __restrict__ NkG)
{
    __shared__ float Nk[KC];
    const int b = blockIdx.x, t = threadIdx.x;
    if (t < KC) Nk[t] = NkG[b * KC + t];
    __syncthreads();
    float s = 0.f;
    for (int k = 0; k < KC; k++) s += Nk[k];
    if (t < KC) logPi[b * KC + t] = logf(Nk[t] / s);
    for (int i = t; i < KC * LD; i += 64) {
        const int k = i >> 6;
        mu[b * KC * LD + i] = musum[b * KC * LD + i] / Nk[k];
        musum[b * KC * LD + i] = 0.f;
    }
    __syncthreads();
    if (t < KC) NkG[b * KC + t] = 0.f;
}

__global__ __launch_bounds__(256)
void kl_kernel(const float* __restrict__ z, const float* __restrict__ stats,
               const float* __restrict__ eps,
               const float* __restrict__ mu, const float* __restrict__ logPi,
               float* __restrict__ klAcc)
{
    __shared__ float muS[KC][65];
    __shared__ float m2lp[KC];
    __shared__ float redS[4];

    const int tile = blockIdx.x, b = blockIdx.y, t = threadIdx.x;

    for (int i = t; i < KC * LD; i += 256) muS[i >> 6][i & 63] = mu[b * KC * LD + i];
    __syncthreads();
    if (t < KC) {
        float s = 0.f;
        for (int l = 0; l < LD; l++) { const float m = muS[t][l]; s = fmaf(m, m, s); }
        m2lp[t] = -0.5f * s + logPi[b * KC + t];
    }
    __syncthreads();

    const int n = tile * 256 + t;
    const int sidx = n / MC, m = n % MC;
    const long bs = (long)b * SEQ + sidx;
    const float* zr = &z[((long)b * NPTS + n) * LD];

    float acc[KC];
#pragma unroll
    for (int k = 0; k < KC; k++) acc[k] = 0.f;
    float x2 = 0.f;
#pragma unroll
    for (int l4 = 0; l4 < 16; l4++) {
        const float4 zv = ((const float4*)zr)[l4];
        x2 = fmaf(zv.x, zv.x, fmaf(zv.y, zv.y, fmaf(zv.z, zv.z, fmaf(zv.w, zv.w, x2))));
#pragma unroll
        for (int k = 0; k < KC; k++) {
            acc[k] = fmaf(zv.x, muS[k][l4 * 4 + 0], acc[k]);
            acc[k] = fmaf(zv.y, muS[k][l4 * 4 + 1], acc[k]);
            acc[k] = fmaf(zv.z, muS[k][l4 * 4 + 2], acc[k]);
            acc[k] = fmaf(zv.w, muS[k][l4 * 4 + 3], acc[k]);
        }
    }
    float mx = -1e30f;
    float llv[KC];
#pragma unroll
    for (int k = 0; k < KC; k++) { llv[k] = acc[k] + m2lp[k]; mx = fmaxf(mx, llv[k]); }
    float s = 0.f;
#pragma unroll
    for (int k = 0; k < KC; k++) s += expf(llv[k] - mx);
    const float log_pz = -0.5f * x2 + mx + logf(s) + LD * LOG_NORM;

    const float* lvr = &stats[bs * 128 + 64];
    const float* er = &eps[(bs * MC + m) * LD];
    float slv = 0.f, se2 = 0.f;
#pragma unroll
    for (int l4 = 0; l4 < 16; l4++) {
        const float4 lv = ((const float4*)lvr)[l4];
        slv += lv.x + lv.y + lv.z + lv.w;
        const float4 e = ((const float4*)er)[l4];
        se2 = fmaf(e.x, e.x, fmaf(e.y, e.y, fmaf(e.z, e.z, fmaf(e.w, e.w, se2))));
    }
    const float log_qz = -0.5f * (slv + se2) + LD * LOG_NORM;

    float v = log_qz - log_pz;
    v = warpReduceSum(v);
    if ((t & 63) == 0) redS[t >> 6] = v;
    __syncthreads();
    if (t == 0) atomicAdd(klAcc, redS[0] + redS[1] + redS[2] + redS[3]);
}

__global__ void finalize(const float* __restrict__ scal, float* __restrict__ out)
{
    if (threadIdx.x == 0) {
        out[0] = scal[0] * (1.f / (float)NROWS);
        out[1] = scal[1] * (1.f / (float)NROWS);
    }
}

// ---------------------------------------------------------------------------
extern "C" void kernel_launch(void* const* d_in, const int* in_sizes, int n_in,
                              void* d_out, int out_size, void* d_ws, size_t ws_size,
                              hipStream_t stream)
{
    const float* H   = (const float*)d_in[0];
    const float* eps = (const float*)d_in[1];
    const float* wq  = (const float*)d_in[2];
    const float* bq  = (const float*)d_in[3];
    const float* wk  = (const float*)d_in[4];
    const float* bk  = (const float*)d_in[5];
    const float* wv  = (const float*)d_in[6];
    const float* bv  = (const float*)d_in[7];
    const float* wo  = (const float*)d_in[8];
    const float* bo  = (const float*)d_in[9];
    const float* wz  = (const float*)d_in[10];
    const float* bz  = (const float*)d_in[11];
    const float* w1  = (const float*)d_in[12];
    const float* b1  = (const float*)d_in[13];
    const float* w2  = (const float*)d_in[14];
    const float* b2  = (const float*)d_in[15];
    const float* w3  = (const float*)d_in[16];
    const float* b3  = (const float*)d_in[17];
    const int* init_idx = (const int*)d_in[18];
    float* out = (float*)d_out;
    float* wsf = (float*)d_ws;

    // ---- workspace layout (float slots), total 18,984,960 floats = 75.9 MB
    const long o_scal  = 0;
    const long o_NkG   = 1024;
    const long o_musum = 2048;
    const long o_logpi = 23552;
    const long o_mu    = 24576;
    const long o_q     = 45056;      // (h2 at MAB2-oproj; z16 in decoder)
    const long o_k     = 2142208;    // (d1 in decoder)
    const long o_vT    = 4239360;
    const long o_o     = 6336512;
    const long o_h1    = 8433664;    // (h0 then h1; d2 in decoder)
    const long o_sc    = 10530816;   // free region (d2 tail in decoder)
    const long o_wqkvT = 14725120;   // (w1T/w2T/w3T in decoder)
    const long o_woT   = 15511552;
    const long o_wzT   = 15773696;
    const long o_st    = 15839232;
    const long o_zb    = 16363520;   // -> end 18984960

    const long PL = (long)BS_TOT * DIM;  // 2097152 elements per plane
    bf* qh  = (bf*)(wsf + o_q);   bf* ql  = qh + PL;
    bf* kh  = (bf*)(wsf + o_k);   bf* kl_ = kh + PL;
    bf* vTh = (bf*)(wsf + o_vT);  bf* vTl = vTh + PL;
    bf* oh  = (bf*)(wsf + o_o);   bf* ol  = oh + PL;
    bf* h1h = (bf*)(wsf + o_h1);  bf* h1l = h1h + PL;   // h0 then h1
    bf* h2h = qh;                 bf* h2l = ql;         // alias q (dead then)
    bf* wqkvTh = (bf*)(wsf + o_wqkvT); bf* wqkvTl = wqkvTh + 1536L * 512;
    bf* woTh = (bf*)(wsf + o_woT);     bf* woTl = woTh + 512L * 512;
    bf* wzTh = (bf*)(wsf + o_wzT);     bf* wzTl = wzTh + 128L * 512;
    float* st = wsf + o_st;
    float* zb = wsf + o_zb;
    float* scal = wsf + o_scal;
    // decoder overlays
    bf* z16 = qh;                                   // q region
    bf* w1T = wqkvTh;                               // 1024x64
    bf* w2T = w1T + 1024L * 64;                     // 1024x1024
    bf* w3T = w2T + 1024L * 1024;                   // 512x1024
    bf* d1  = (bf*)(wsf + o_k);                     // 10240x1024 (k..o regions)
    bf* d2  = (bf*)(wsf + o_h1);                    // 10240x1024 (h1+sc regions)

    hipMemsetAsync(scal, 0, 64, stream);

    const dim3 blk(256);

    // ---- input H -> split planes (h1 region serves as h0) ----
    conv_split_flat<<<(int)((PL + 255) / 256), blk, 0, stream>>>(H, h1h, h1l, (int)PL);

    // ---- 2x MAB on split-bf16 MFMA ----
    for (int i = 0; i < 2; i++) {
        const long woff = (long)i * DIM * DIM, boff = (long)i * DIM;
        conv_mab_weights<<<4096, blk, 0, stream>>>(
            wq + woff, wk + woff, wv + woff, wo + woff,
            wqkvTh, wqkvTl, woTh, woTl);

        // QKV fused: [q|k|vT] = h @ [wq|wk|wv] + b
        gemm3<0><<<dim3(12, 32), blk, 0, stream>>>(
            h1h, h1l, wqkvTh, wqkvTl, 512, 512, 512,
            bq + boff, bk + boff, bv + boff, nullptr,
            qh, ql, kh, kl_, vTh, vTl, nullptr, nullptr);
        // fused attention: o = q + softmax(q k^T / sqrt(D)) @ v
        attn_fused<<<dim3(4, 64), blk, 0, stream>>>(qh, ql, kh, kl_, vTh, vTl, oh, ol);
        // h = o + relu(o @ wo + bo)
        bf* houth = (i == 0) ? h1h : h2h;
        bf* houtl = (i == 0) ? h1l : h2l;
        gemm3<3><<<dim3(4, 32), blk, 0, stream>>>(
            oh, ol, woTh, woTl, 512, 512, 512,
            bo + boff, nullptr, nullptr, nullptr,
            houth, houtl, nullptr, nullptr, nullptr, nullptr, oh, ol);
    }

    // ---- misc weights (wz split + decoder plain) in one launch ----
    conv_misc_weights<<<6656, blk, 0, stream>>>(wz, wzTh, wzTl, w1, w1T, w2, w2T, w3, w3T);

    // ---- stats = h2 @ wz + bz (fp32 out) ----
    gemm3<4><<<dim3(1, 32), blk, 0, stream>>>(
        h2h, h2l, wzTh, wzTl, 512, 512, 512,
        bz, nullptr, nullptr, st,
        nullptr, nullptr, nullptr, nullptr, nullptr, nullptr, nullptr, nullptr);

    // ---- z (fp32 exact + bf16 copy; z16 overlays dead q region) ----
    zgen<<<2560, blk, 0, stream>>>(st, eps, zb, z16);

    // ---- decoder MLP + fused rec_loss, 4 chunks of 10240 rows ----
    for (int c = 0; c < 4; c++) {
        const long rows0 = (long)c * 10240;
        gemm_mfma<false><<<dim3(8, 80), blk, 0, stream>>>(
            z16 + rows0 * LD, w1T, d1, b1, nullptr, nullptr, 64, 1024, 0);
        gemm_mfma<false><<<dim3(8, 80), blk, 0, stream>>>(
            d1, w2T, d2, b2, nullptr, nullptr, 1024, 1024, 0);
        gemm_mfma<true><<<dim3(4, 80), blk, 0, stream>>>(
            d2, w3T, nullptr, b3, H, scal + 0, 1024, 512, (int)rows0);
    }

    // ---- EM (fp32, exact) ----
    em_init<<<16, blk, 0, stream>>>(zb, init_idx, wsf + o_mu, wsf + o_logpi,
                                    wsf + o_musum, wsf + o_NkG);
    for (int it = 0; it < 5; it++) {
        em_step<<<dim3(10, 16), blk, 0, stream>>>(zb, wsf + o_mu, wsf + o_logpi,
                                                  wsf + o_musum, wsf + o_NkG);
        em_update<<<16, 64, 0, stream>>>(wsf + o_mu, wsf + o_logpi,
                                         wsf + o_musum, wsf + o_NkG);
    }

    // ---- KL (fp32, exact) ----
    kl_kernel<<<dim3(10, 16), blk, 0, stream>>>(zb, st, eps, wsf + o_mu,
                                                wsf + o_logpi, scal + 1);

    finalize<<<1, 64, 0, stream>>>(scal, out);
}